// Round 21
// baseline (564.494 us; speedup 1.0000x reference)
//
#include <hip/hip_runtime.h>
#include <hip/hip_bf16.h>

typedef __attribute__((ext_vector_type(8))) short  bf16x8;
typedef __attribute__((ext_vector_type(4))) float  f32x4;
typedef __attribute__((ext_vector_type(8))) unsigned short u16x8;
typedef __attribute__((ext_vector_type(4))) unsigned short u16x4;

__device__ __forceinline__ unsigned short f2b(float f) {
    unsigned int u = __builtin_bit_cast(unsigned int, f);
    u += 0x7FFFu + ((u >> 16) & 1u);
    return (unsigned short)(u >> 16);
}
__device__ __forceinline__ float b2f(unsigned short u) {
    return __builtin_bit_cast(float, (unsigned int)u << 16);
}
// sigmoid-form GELU: x*sigmoid(1.702x). ~5 VALU ops.
__device__ __forceinline__ float gelu_fast(float x) {
    float d = 1.0f + __expf(-1.702f * x);
    return x * __builtin_amdgcn_rcpf(d);
}
// windowed row m -> original row (b*65536 + y*256 + x)
__device__ __forceinline__ int wperm(int m) {
    int w = m >> 6, n = m & 63;
    int b = w >> 10, wy = (w >> 5) & 31, wx = w & 31;
    int y = wy * 8 + (n >> 3), xx = wx * 8 + (n & 7);
    return (b << 16) + (y << 8) + xx;
}

__device__ __forceinline__ void gload_lds16(const void* g, void* l) {
    __builtin_amdgcn_global_load_lds(
        (const __attribute__((address_space(1))) void*)g,
        (__attribute__((address_space(3))) void*)l, 16, 0, 0);
}

// ---------------- prep kernels ----------------
__global__ void transpose_w(const float* __restrict__ in, unsigned short* __restrict__ out,
                            int K, int N) {
    int i = blockIdx.x * 256 + threadIdx.x;
    if (i >= K * N) return;
    int n = i / K, k = i - n * K;
    out[i] = f2b(in[k * N + n]);
}

__global__ void transpose_wf(const float* __restrict__ in, float* __restrict__ out,
                             int K, int N) {
    int i = blockIdx.x * 256 + threadIdx.x;
    if (i >= K * N) return;
    int n = i / K, k = i - n * K;
    out[i] = in[k * N + n];
}

__global__ __launch_bounds__(256) void cpb_kernel(
    const float* __restrict__ scale, const float* __restrict__ w1, const float* __restrict__ b1,
    const float* __restrict__ w2, const float* __restrict__ b2, float* __restrict__ btab) {
    int t = threadIdx.x;
    if (t >= 225) return;
    int i = t / 15, j = t - (t / 15) * 15;
    float ti = (i - 7) * (8.0f / 7.0f);
    float tj = (j - 7) * (8.0f / 7.0f);
    float s0 = scale[0], s1 = scale[1];
    float acc[6];
    #pragma unroll
    for (int h = 0; h < 6; ++h) acc[h] = b2[h];
    for (int k = 0; k < 512; ++k) {
        float hv = ti * w1[k] + tj * w1[512 + k] + s0 * w1[1024 + k] + s1 * w1[1536 + k] + b1[k];
        hv = fmaxf(hv, 0.f);
        #pragma unroll
        for (int h = 0; h < 6; ++h) acc[h] += hv * w2[k * 6 + h];
    }
    #pragma unroll
    for (int h = 0; h < 6; ++h) btab[t * 6 + h] = acc[h];
}

// ---------------- GEMM: M-tile 64, full-K A-panel in LDS, 8 waves ----------
// MODE 0 only in this build: A = LN1(x[wperm]) in-block -> q/k/v scatter.
template<int MODE>
__global__ __launch_bounds__(512) void gemm64(
    const float* __restrict__ Af, const unsigned short* __restrict__ Ab,
    const float* __restrict__ stats, const float* __restrict__ lng, const float* __restrict__ lnb,
    const unsigned short* __restrict__ Bt, const float* __restrict__ bias,
    unsigned short* __restrict__ oq, unsigned short* __restrict__ ok2, unsigned short* __restrict__ ov,
    const float* __restrict__ resid, float* __restrict__ ofp, unsigned short* __restrict__ obf,
    float* __restrict__ ostat) {
    constexpr int NCT = (MODE == 0) ? 3 : (MODE == 2) ? 4 : 1;
    __shared__ __align__(16) unsigned short Asw[3 * 64 * 64];    // 24576 B
    __shared__ __align__(16) unsigned short Bsw[2 * 192 * 64];   // 49152 B
    const int t = threadIdx.x, lane = t & 63, wv8 = t >> 6;
    const int wm = wv8 >> 2, wn = wv8 & 3;           // 2m x 4n
    const int l15 = lane & 15, lq = lane >> 4;
    const int m0 = blockIdx.x * 64;

    int boffs[3];
    #pragma unroll
    for (int s = 0; s < 3; ++s) {
        int row = (wv8 + 8 * s) * 8 + (lane >> 3);
        boffs[s] = row * 192 + ((lane & 7) ^ (lane >> 3)) * 8;
    }
    if constexpr (MODE == 1) {
        #pragma unroll
        for (int s = 0; s < 3; ++s) {
            int si = wv8 + 8 * s;
            int row = (si & 7) * 8 + (lane >> 3);
            int src = (m0 + row) * 192 + (si >> 3) * 64 + ((lane & 7) ^ (lane >> 3)) * 8;
            gload_lds16(Ab + src, (char*)Asw + si * 1024);
        }
    }
    #pragma unroll
    for (int s = 0; s < 3; ++s)   // B (ct0, k0) -> buf 0
        gload_lds16(Bt + boffs[s], (char*)Bsw + (wv8 + 8 * s) * 1024);

    if constexpr (MODE == 0) {    // LN1 in-block: 8 lanes per row, 24 elems each
        int row = t >> 3, oct = t & 7;
        const float* p = Af + (size_t)wperm(m0 + row) * 192 + oct * 24;
        f32x4 v[6];
        float s = 0.f, q = 0.f;
        #pragma unroll
        for (int i = 0; i < 6; ++i) {
            v[i] = *(const f32x4*)(p + i * 4);
            #pragma unroll
            for (int j = 0; j < 4; ++j) { s += v[i][j]; q += v[i][j] * v[i][j]; }
        }
        s += __shfl_xor(s, 1); s += __shfl_xor(s, 2); s += __shfl_xor(s, 4);
        q += __shfl_xor(q, 1); q += __shfl_xor(q, 2); q += __shfl_xor(q, 4);
        float mean = s * (1.f / 192.f);
        float rstd = rsqrtf(q * (1.f / 192.f) - mean * mean + 1e-5f);
        #pragma unroll
        for (int i = 0; i < 6; ++i) {
            int k = oct * 24 + i * 4;
            u16x4 pk;
            #pragma unroll
            for (int j = 0; j < 4; ++j)
                pk[j] = f2b((v[i][j] - mean) * rstd * lng[k + j] + lnb[k + j]);
            int cc = k >> 6, ch = (k >> 2) & 15;
            int byte = cc * 8192 + row * 128 +
                       ((((ch >> 1) ^ (row & 7)) << 4) + ((ch & 1) << 3));
            *(u16x4*)((char*)Asw + byte) = pk;
        }
        asm volatile("s_waitcnt lgkmcnt(0)" ::: "memory");
    }

    const int axor = (l15 & 7) << 4;
    int cur = 0, it = 0;
    for (int ct = 0; ct < NCT; ++ct) {
        f32x4 acc[2][3];
        #pragma unroll
        for (int i = 0; i < 2; ++i)
            #pragma unroll
            for (int j = 0; j < 3; ++j) acc[i][j] = (f32x4){0.f, 0.f, 0.f, 0.f};
        for (int c = 0; c < 3; ++c, ++it) {
            if (it < NCT * 3 - 1) {
                int ctn = (c == 2) ? ct + 1 : ct;
                int cn  = (c == 2) ? 0 : c + 1;
                #pragma unroll
                for (int s = 0; s < 3; ++s)
                    gload_lds16(Bt + (size_t)ctn * 36864 + boffs[s] + cn * 64,
                                (char*)Bsw + (cur ^ 1) * 24576 + (wv8 + 8 * s) * 1024);
                asm volatile("s_waitcnt vmcnt(3)" ::: "memory");
            } else {
                asm volatile("s_waitcnt vmcnt(0)" ::: "memory");
            }
            __builtin_amdgcn_sched_barrier(0);
            __builtin_amdgcn_s_barrier();
            __builtin_amdgcn_sched_barrier(0);
            const char* Al = (const char*)Asw + c * 8192;
            const char* Bl = (const char*)Bsw + cur * 24576;
            #pragma unroll
            for (int kk = 0; kk < 2; ++kk) {
                bf16x8 a[2], bb[3];
                #pragma unroll
                for (int mt = 0; mt < 2; ++mt)
                    a[mt] = *(const bf16x8*)(Al + (wm * 32 + mt * 16 + l15) * 128 +
                                             ((kk << 6) ^ (lq << 4) ^ axor));
                #pragma unroll
                for (int nt = 0; nt < 3; ++nt)
                    bb[nt] = *(const bf16x8*)(Bl + (wn * 48 + nt * 16 + l15) * 128 +
                                              ((kk << 6) ^ (lq << 4) ^ axor));
                #pragma unroll
                for (int mt = 0; mt < 2; ++mt)
                    #pragma unroll
                    for (int nt = 0; nt < 3; ++nt)
                        acc[mt][nt] = __builtin_amdgcn_mfma_f32_16x16x32_bf16(a[mt], bb[nt], acc[mt][nt], 0, 0, 0);
            }
            __builtin_amdgcn_sched_barrier(0);
            __builtin_amdgcn_s_barrier();
            cur ^= 1;
        }
        if constexpr (MODE == 0) {
            unsigned short* dst = (ct == 0) ? oq : (ct == 1) ? ok2 : ov;
            float qs = (ct == 0) ? 0.17677669529663689f : 1.0f;
            #pragma unroll
            for (int mt = 0; mt < 2; ++mt)
                #pragma unroll
                for (int nt = 0; nt < 3; ++nt)
                    #pragma unroll
                    for (int r = 0; r < 4; ++r) {
                        int m = m0 + wm * 32 + mt * 16 + lq * 4 + r;
                        int col = wn * 48 + nt * 16 + l15;
                        float v = (acc[mt][nt][r] + bias[ct * 192 + col]) * qs;
                        int head = col >> 5, d = col & 31;
                        int w = m >> 6, n = m & 63;
                        dst[((size_t)(w * 6 + head) * 64 + n) * 32 + d] = f2b(v);
                    }
        }
    }
    (void)stats; (void)resid; (void)ofp; (void)obf; (void)ostat;
}

// ---- fused: proj GEMM + residual + LN2 (in-block) + fc1 GEMM + gelu -------
// Phase 1 (= old MODE1): A = attn-out via gload_lds, B = projT (1 col-tile).
// Epilogue keeps w = resid+acc+bias in regs, writes out, reduces row stats
// in LDS, then normalizes the HELD values into the swizzled Asw panel.
// Phase 2 (= old MODE2): NCT=4 over fc1T, m1 = gelu(A@W+b). Eliminates the
// 100MB out re-read, stats round-trip, A re-staging, and one launch.
__global__ __launch_bounds__(512) void gemm_fused12(
    const unsigned short* __restrict__ Ab, const float* __restrict__ resid,
    const unsigned short* __restrict__ projT, const float* __restrict__ projb,
    const unsigned short* __restrict__ fc1T, const float* __restrict__ fc1b,
    const float* __restrict__ n2g, const float* __restrict__ n2b,
    float* __restrict__ ofp, unsigned short* __restrict__ obf) {
    __shared__ __align__(16) unsigned short Asw[3 * 64 * 64];    // 24576 B
    __shared__ __align__(16) unsigned short Bsw[2 * 192 * 64];   // 49152 B
    __shared__ float sred[64 * 8];                               // 2048 B
    __shared__ float srow[64 * 2];                               // 512 B
    const int t = threadIdx.x, lane = t & 63, wv8 = t >> 6;
    const int wm = wv8 >> 2, wn = wv8 & 3;
    const int l15 = lane & 15, lq = lane >> 4;
    const int m0 = blockIdx.x * 64;

    int boffs[3];
    #pragma unroll
    for (int s = 0; s < 3; ++s) {
        int row = (wv8 + 8 * s) * 8 + (lane >> 3);
        boffs[s] = row * 192 + ((lane & 7) ^ (lane >> 3)) * 8;
    }
    #pragma unroll
    for (int s = 0; s < 3; ++s) {   // A panel (attn out)
        int si = wv8 + 8 * s;
        int row = (si & 7) * 8 + (lane >> 3);
        int src = (m0 + row) * 192 + (si >> 3) * 64 + ((lane & 7) ^ (lane >> 3)) * 8;
        gload_lds16(Ab + src, (char*)Asw + si * 1024);
    }
    #pragma unroll
    for (int s = 0; s < 3; ++s)     // proj B chunk 0 -> buf 0
        gload_lds16(projT + boffs[s], (char*)Bsw + (wv8 + 8 * s) * 1024);

    const int axor = (l15 & 7) << 4;
    int cur = 0;

    // ---------------- phase 1: proj ----------------
    f32x4 acc[2][3];
    #pragma unroll
    for (int i = 0; i < 2; ++i)
        #pragma unroll
        for (int j = 0; j < 3; ++j) acc[i][j] = (f32x4){0.f, 0.f, 0.f, 0.f};
    for (int c = 0; c < 3; ++c) {
        if (c < 2) {
            #pragma unroll
            for (int s = 0; s < 3; ++s)
                gload_lds16(projT + boffs[s] + (c + 1) * 64,
                            (char*)Bsw + (cur ^ 1) * 24576 + (wv8 + 8 * s) * 1024);
        } else {   // prefetch fc1 ct0 chunk0 (lands during epilogue)
            #pragma unroll
            for (int s = 0; s < 3; ++s)
                gload_lds16(fc1T + boffs[s],
                            (char*)Bsw + (cur ^ 1) * 24576 + (wv8 + 8 * s) * 1024);
        }
        asm volatile("s_waitcnt vmcnt(3)" ::: "memory");
        __builtin_amdgcn_sched_barrier(0);
        __builtin_amdgcn_s_barrier();
        __builtin_amdgcn_sched_barrier(0);
        const char* Al = (const char*)Asw + c * 8192;
        const char* Bl = (const char*)Bsw + cur * 24576;
        #pragma unroll
        for (int kk = 0; kk < 2; ++kk) {
            bf16x8 a[2], bb[3];
            #pragma unroll
            for (int mt = 0; mt < 2; ++mt)
                a[mt] = *(const bf16x8*)(Al + (wm * 32 + mt * 16 + l15) * 128 +
                                         ((kk << 6) ^ (lq << 4) ^ axor));
            #pragma unroll
            for (int nt = 0; nt < 3; ++nt)
                bb[nt] = *(const bf16x8*)(Bl + (wn * 48 + nt * 16 + l15) * 128 +
                                          ((kk << 6) ^ (lq << 4) ^ axor));
            #pragma unroll
            for (int mt = 0; mt < 2; ++mt)
                #pragma unroll
                for (int nt = 0; nt < 3; ++nt)
                    acc[mt][nt] = __builtin_amdgcn_mfma_f32_16x16x32_bf16(a[mt], bb[nt], acc[mt][nt], 0, 0, 0);
        }
        __builtin_amdgcn_sched_barrier(0);
        __builtin_amdgcn_s_barrier();
        cur ^= 1;
    }
    // ---- epilogue 1: out write + stats (w held in regs) ----
    float w[2][3][4];
    #pragma unroll
    for (int mt = 0; mt < 2; ++mt) {
        #pragma unroll
        for (int r = 0; r < 4; ++r) {
            int row = wm * 32 + mt * 16 + lq * 4 + r;
            int r2 = wperm(m0 + row);
            float s = 0.f, q = 0.f;
            #pragma unroll
            for (int nt = 0; nt < 3; ++nt) {
                int col = wn * 48 + nt * 16 + l15;
                size_t idx = (size_t)r2 * 192 + col;
                float wv = resid[idx] + acc[mt][nt][r] + projb[col];
                ofp[idx] = wv;
                w[mt][nt][r] = wv;
                s += wv;
                q += wv * wv;
            }
            #pragma unroll
            for (int off = 1; off < 16; off <<= 1) {
                s += __shfl_xor(s, off);
                q += __shfl_xor(q, off);
            }
            if (l15 == 0) {
                sred[row * 8 + wn * 2]     = s;
                sred[row * 8 + wn * 2 + 1] = q;
            }
        }
    }
    __syncthreads();
    if (t < 64) {
        float s = sred[t * 8] + sred[t * 8 + 2] + sred[t * 8 + 4] + sred[t * 8 + 6];
        float q = sred[t * 8 + 1] + sred[t * 8 + 3] + sred[t * 8 + 5] + sred[t * 8 + 7];
        float mean = s * (1.f / 192.f);
        float var = q * (1.f / 192.f) - mean * mean;
        srow[t * 2] = mean;
        srow[t * 2 + 1] = rsqrtf(var + 1e-5f);
    }
    __syncthreads();
    // ---- normalize held values into swizzled Asw panel ----
    {
        float g3[3], b3[3];
        #pragma unroll
        for (int nt = 0; nt < 3; ++nt) {
            int col = wn * 48 + nt * 16 + l15;
            g3[nt] = n2g[col];
            b3[nt] = n2b[col];
        }
        #pragma unroll
        for (int mt = 0; mt < 2; ++mt)
            #pragma unroll
            for (int r = 0; r < 4; ++r) {
                int row = wm * 32 + mt * 16 + lq * 4 + r;
                float mean = srow[row * 2], rstd = srow[row * 2 + 1];
                #pragma unroll
                for (int nt = 0; nt < 3; ++nt) {
                    int k = wn * 48 + nt * 16 + l15;
                    float nv = (w[mt][nt][r] - mean) * rstd * g3[nt] + b3[nt];
                    int cc = k >> 6, kk = k & 63;
                    int byte = cc * 8192 + row * 128 +
                               ((((kk >> 3) ^ (row & 7)) << 4) + (kk & 7) * 2);
                    *(unsigned short*)((char*)Asw + byte) = f2b(nv);
                }
            }
    }
    __syncthreads();   // A panel ready (also drained the fc1 ct0c0 prefetch)

    // ---------------- phase 2: fc1, NCT = 4 ----------------
    for (int ct = 0; ct < 4; ++ct) {
        f32x4 a2[2][3];
        #pragma unroll
        for (int i = 0; i < 2; ++i)
            #pragma unroll
            for (int j = 0; j < 3; ++j) a2[i][j] = (f32x4){0.f, 0.f, 0.f, 0.f};
        for (int c = 0; c < 3; ++c) {
            int it = ct * 3 + c;
            if (it < 11) {
                int ctn = (c == 2) ? ct + 1 : ct;
                int cn  = (c == 2) ? 0 : c + 1;
                #pragma unroll
                for (int s = 0; s < 3; ++s)
                    gload_lds16(fc1T + (size_t)ctn * 36864 + boffs[s] + cn * 64,
                                (char*)Bsw + (cur ^ 1) * 24576 + (wv8 + 8 * s) * 1024);
                asm volatile("s_waitcnt vmcnt(3)" ::: "memory");
            } else {
                asm volatile("s_waitcnt vmcnt(0)" ::: "memory");
            }
            __builtin_amdgcn_sched_barrier(0);
            __builtin_amdgcn_s_barrier();
            __builtin_amdgcn_sched_barrier(0);
            const char* Al = (const char*)Asw + c * 8192;
            const char* Bl = (const char*)Bsw + cur * 24576;
            #pragma unroll
            for (int kk = 0; kk < 2; ++kk) {
                bf16x8 a[2], bb[3];
                #pragma unroll
                for (int mt = 0; mt < 2; ++mt)
                    a[mt] = *(const bf16x8*)(Al + (wm * 32 + mt * 16 + l15) * 128 +
                                             ((kk << 6) ^ (lq << 4) ^ axor));
                #pragma unroll
                for (int nt = 0; nt < 3; ++nt)
                    bb[nt] = *(const bf16x8*)(Bl + (wn * 48 + nt * 16 + l15) * 128 +
                                              ((kk << 6) ^ (lq << 4) ^ axor));
                #pragma unroll
                for (int mt = 0; mt < 2; ++mt)
                    #pragma unroll
                    for (int nt = 0; nt < 3; ++nt)
                        a2[mt][nt] = __builtin_amdgcn_mfma_f32_16x16x32_bf16(a[mt], bb[nt], a2[mt][nt], 0, 0, 0);
            }
            __builtin_amdgcn_sched_barrier(0);
            __builtin_amdgcn_s_barrier();
            cur ^= 1;
        }
        #pragma unroll
        for (int mt = 0; mt < 2; ++mt)
            #pragma unroll
            for (int nt = 0; nt < 3; ++nt)
                #pragma unroll
                for (int r = 0; r < 4; ++r) {
                    int m = m0 + wm * 32 + mt * 16 + lq * 4 + r;
                    int col = wn * 48 + nt * 16 + l15;
                    obf[(size_t)wperm(m) * 768 + ct * 192 + col] =
                        f2b(gelu_fast(a2[mt][nt][r] + fc1b[ct * 192 + col]));
                }
    }
}

// ---------------- attention: one wave per (window, head) ----------------
__global__ __launch_bounds__(64) void attn_win(
    const unsigned short* __restrict__ qb, const unsigned short* __restrict__ kb,
    const unsigned short* __restrict__ vb, const float* __restrict__ btab,
    unsigned short* __restrict__ ao) {
    __shared__ float sb[225];
    __shared__ __align__(16) unsigned short pl[64 * 72];
    __shared__ __align__(16) unsigned short vT[32 * 72];
    const int bid = blockIdx.x;            // = w*6 + h
    const int w = bid / 6, h = bid - w * 6;
    const int lane = threadIdx.x;
    const int l15 = lane & 15, lq = lane >> 4;

    for (int i = lane; i < 225; i += 64) sb[i] = btab[i * 6 + h];

    const unsigned short* qp = qb + (size_t)bid * 2048;
    const unsigned short* kp = kb + (size_t)bid * 2048;
    const unsigned short* vp = vb + (size_t)bid * 2048;

    bf16x8 qf[4], kf[4];
    #pragma unroll
    for (int i = 0; i < 4; ++i) {
        qf[i] = *(const bf16x8*)(qp + (i * 16 + l15) * 32 + lq * 8);
        kf[i] = *(const bf16x8*)(kp + (i * 16 + l15) * 32 + lq * 8);
    }
    #pragma unroll
    for (int i = 0; i < 4; ++i) {  // V transposed into LDS
        int c = lane + i * 64;
        int mr = c >> 2, d0 = (c & 3) * 8;
        u16x8 v = *(const u16x8*)(vp + mr * 32 + d0);
        #pragma unroll
        for (int j = 0; j < 8; ++j) vT[(d0 + j) * 72 + mr] = v[j];
    }
    f32x4 s[4][4];
    #pragma unroll
    for (int mt = 0; mt < 4; ++mt)
        #pragma unroll
        for (int nt = 0; nt < 4; ++nt)
            s[mt][nt] = __builtin_amdgcn_mfma_f32_16x16x32_bf16(
                qf[mt], kf[nt], (f32x4){0.f, 0.f, 0.f, 0.f}, 0, 0, 0);
    __syncthreads();
    // bias + softmax (rows over 16 lanes x 4 col-tiles)
    #pragma unroll
    for (int mt = 0; mt < 4; ++mt) {
        #pragma unroll
        for (int r = 0; r < 4; ++r) {
            int n = mt * 16 + lq * 4 + r;
            int ny = n >> 3, nx = n & 7;
            float sv[4];
            float mx = -1e30f;
            #pragma unroll
            for (int nt = 0; nt < 4; ++nt) {
                int m = nt * 16 + l15;
                int idx = (ny - (m >> 3) + 7) * 15 + (nx - (m & 7) + 7);
                float val = s[mt][nt][r] + sb[idx];
                sv[nt] = val;
                mx = fmaxf(mx, val);
            }
            #pragma unroll
            for (int off = 1; off < 16; off <<= 1) mx = fmaxf(mx, __shfl_xor(mx, off));
            float sum = 0.f;
            #pragma unroll
            for (int nt = 0; nt < 4; ++nt) { sv[nt] = __expf(sv[nt] - mx); sum += sv[nt]; }
            #pragma unroll
            for (int off = 1; off < 16; off <<= 1) sum += __shfl_xor(sum, off);
            float inv = 1.f / sum;
            #pragma unroll
            for (int nt = 0; nt < 4; ++nt)
                pl[n * 72 + nt * 16 + l15] = f2b(sv[nt] * inv);
        }
    }
    __syncthreads();
    f32x4 o[4][2];
    #pragma unroll
    for (int i = 0; i < 4; ++i)
        #pragma unroll
        for (int j = 0; j < 2; ++j) o[i][j] = (f32x4){0.f, 0.f, 0.f, 0.f};
    #pragma unroll
    for (int mt = 0; mt < 4; ++mt)
        #pragma unroll
        for (int kk = 0; kk < 2; ++kk) {
            bf16x8 a = *(bf16x8*)&pl[(mt * 16 + l15) * 72 + kk * 32 + lq * 8];
            #pragma unroll
            for (int dt = 0; dt < 2; ++dt) {
                bf16x8 b = *(bf16x8*)&vT[(dt * 16 + l15) * 72 + kk * 32 + lq * 8];
                o[mt][dt] = __builtin_amdgcn_mfma_f32_16x16x32_bf16(a, b, o[mt][dt], 0, 0, 0);
            }
        }
    #pragma unroll
    for (int mt = 0; mt < 4; ++mt)
        #pragma unroll
        for (int dt = 0; dt < 2; ++dt)
            #pragma unroll
            for (int r = 0; r < 4; ++r) {
                int n = mt * 16 + lq * 4 + r;
                int d = dt * 16 + l15;
                ao[((size_t)w * 64 + n) * 192 + h * 32 + d] = f2b(o[mt][dt][r]);
            }
}

// -------- fused depthwise 3x3 conv + gelu + fc2 + residual ------------------
// v14 (proven 199us): tile 32x*4y, vertical-pair threads share tap weights.
__global__ __launch_bounds__(512) void conv_fc2_v14(
    const unsigned short* __restrict__ m1, const float* __restrict__ dwwTf,
    const float* __restrict__ dwb, const unsigned short* __restrict__ fc2T,
    const float* __restrict__ fc2b, float* __restrict__ out) {
    __shared__ __align__(16) unsigned short Xs[26 * 512];      // 26624 B (13056 used)
    __shared__ __align__(16) unsigned short As[128 * 72];      // 18432 B
    __shared__ __align__(16) unsigned short Bsw[192 * 64];     // 24576 B
    const int t = threadIdx.x;
    const int g = ((blockIdx.x & 7) << 7) + (blockIdx.x >> 3); // 1024 blocks, XCD bands
    const int b = g >> 9, yt = (g >> 3) & 63, xq = g & 7;
    const int y0 = yt * 4, x0 = xq * 32;
    const int cg = t & 7, lx = t >> 3;               // lx in [0,64)
    const int xx = lx & 31, yy0 = lx >> 5;           // output rows yy0, yy0+2
    const size_t ibase = (size_t)b * 65536;

    const int lane = t & 63, wv8 = t >> 6;           // wave 0..7
    const int wm = wv8 >> 1, wn = wv8 & 1;           // 4m x 2n wave grid
    const int l15 = lane & 15, lq = lane >> 4;

    // Xs stage source offsets: 26 segs of 512 elems, 4 slots/wave (skip seg>=26)
    int xoff[4];
    #pragma unroll
    for (int s = 0; s < 4; ++s) {
        int seg = wv8 + 8 * s;
        int e = seg * 512 + lane * 8;
        e = min(e, 13048);                           // clamp (pad lanes of seg 25)
        int row = e / 2176;
        int rem = e - row * 2176;
        int px = rem >> 6, ch = rem & 63;
        int gy = min(max(y0 - 1 + row, 0), 255);
        int gx = min(max(x0 - 1 + px, 0), 255);
        xoff[s] = ((b << 16) + (gy << 8) + gx) * 768 + ch;
    }
    int boff[3];
    #pragma unroll
    for (int s = 0; s < 3; ++s) {
        int row = (wv8 + 8 * s) * 8 + (lane >> 3);
        boff[s] = row * 768 + ((lane & 7) ^ (lane >> 3)) * 8;
    }

    f32x4 acc[2][6];
    #pragma unroll
    for (int i = 0; i < 2; ++i)
        #pragma unroll
        for (int j = 0; j < 6; ++j) acc[i][j] = (f32x4){0.f, 0.f, 0.f, 0.f};

    // prologue: stage chunk 0
    #pragma unroll
    for (int s = 0; s < 4; ++s)
        if (wv8 + 8 * s < 26)
            gload_lds16(m1 + xoff[s], (char*)Xs + (wv8 + 8 * s) * 1024);
    #pragma unroll
    for (int s = 0; s < 3; ++s)
        gload_lds16(fc2T + boff[s], (char*)Bsw + (wv8 + 8 * s) * 1024);

    const int xb = xx * 128 + cg * 16;               // byte offset within a row
    const int gxp = x0 + xx;
    const bool xok0 = gxp >= 1;
    const bool xok2 = gxp <= 254;
    const int oy0 = y0 + yy0;                        // output rows oy0, oy0+2
    const int o00 = (lq * 16) ^ ((l15 & 7) << 4);
    const int brow = (wn * 96 + l15) * 128;

    for (int k0 = 0; k0 < 768; k0 += 64) {
        const int c0 = k0 + cg * 8;
        asm volatile("s_waitcnt vmcnt(0)" ::: "memory");
        __syncthreads();                               // b1: Xs,Bsw ready
        // ---- conv: 2 output px (rows yy0, yy0+2), shared tap weights ----
        float a0[8], a1[8];
        #pragma unroll
        for (int j = 0; j < 8; ++j) { a0[j] = 0.f; a1[j] = 0.f; }
        #pragma unroll
        for (int kx = 0; kx < 3; ++kx) {
            if (kx == 0 && !xok0) continue;
            if (kx == 2 && !xok2) continue;
            #pragma unroll
            for (int ky = 0; ky < 3; ++ky) {
                const float* wp = dwwTf + (ky * 3 + kx) * 768 + c0;
                f32x4 w0 = *(const f32x4*)wp;
                f32x4 w1 = *(const f32x4*)(wp + 4);
                if ((unsigned)(oy0 + ky - 1) < 256u) {
                    u16x8 in = *(const u16x8*)((const char*)Xs +
                        (yy0 + ky) * 4352 + xb + kx * 128);
                    #pragma unroll
                    for (int j = 0; j < 4; ++j) {
                        a0[j]     += b2f(in[j]) * w0[j];
                        a0[4 + j] += b2f(in[4 + j]) * w1[j];
                    }
                }
                if ((unsigned)(oy0 + ky + 1) < 256u) {
                    u16x8 in = *(const u16x8*)((const char*)Xs +
                        (yy0 + 2 + ky) * 4352 + xb + kx * 128);
                    #pragma unroll
                    for (int j = 0; j < 4; ++j) {
                        a1[j]     += b2f(in[j]) * w0[j];
                        a1[4 + j] += b2f(in[4 + j]) * w1[j];
                    }
                }
            }
        }
        {
            f32x4 b0 = *(const f32x4*)(dwb + c0);
            f32x4 b1 = *(const f32x4*)(dwb + c0 + 4);
            u16x8 o0, o1;
            #pragma unroll
            for (int j = 0; j < 4; ++j) {
                o0[j]     = f2b(gelu_fast(a0[j] + b0[j]));
                o0[4 + j] = f2b(gelu_fast(a0[4 + j] + b1[j]));
                o1[j]     = f2b(gelu_fast(a1[j] + b0[j]));
                o1[4 + j] = f2b(gelu_fast(a1[4 + j] + b1[j]));
            }
            *(u16x8*)&As[lx * 72 + cg * 8] = o0;            // px = yy0*32+xx = lx
            *(u16x8*)&As[(lx + 64) * 72 + cg * 8] = o1;     // px = (yy0+2)*32+xx
        }
        __syncthreads();                               // b2: As ready, Xs free
        if (k0 < 704) {   // Xs prefetch overlaps the MFMA phase
            #pragma unroll
            for (int s = 0; s < 4; ++s)
                if (wv8 + 8 * s < 26)
                    gload_lds16(m1 + xoff[s] + k0 + 64,
                                (char*)Xs + (wv8 + 8 * s) * 1024);
        }
        // ---- MFMA: wave tile 32 px x 96 ch ----
        #pragma unroll
        for (int kk = 0; kk < 2; ++kk) {
            bf16x8 af[2];
            #pragma unroll
            for (int mt = 0; mt < 2; ++mt)
                af[mt] = *(bf16x8*)&As[(wm * 32 + mt * 16 + l15) * 72 + kk * 32 + lq * 8];
            #pragma unroll
            for (int nt = 0; nt < 6; ++nt) {
                bf16x8 bb = *(const bf16x8*)((const char*)Bsw + brow + nt * 2048 + (o00 ^ (kk << 6)));
                #pragma unroll
                for (int mt = 0; mt < 2; ++mt)
                    acc[mt][nt] = __builtin_amdgcn_mfma_f32_16x16x32_bf16(af[mt], bb, acc[mt][nt], 0, 0, 0);
            }
        }
        __syncthreads();                               // b3: As,Bsw free
        if (k0 < 704) {
            #pragma unroll
            for (int s = 0; s < 3; ++s)
                gload_lds16(fc2T + boff[s] + k0 + 64, (char*)Bsw + (wv8 + 8 * s) * 1024);
        }
    }
    #pragma unroll
    for (int mt = 0; mt < 2; ++mt)
        #pragma unroll
        for (int nt = 0; nt < 6; ++nt)
            #pragma unroll
            for (int r = 0; r < 4; ++r) {
                int ml = wm * 32 + mt * 16 + lq * 4 + r;    // px in [0,128)
                int py = ml >> 5, lxx = ml & 31;
                int col = wn * 96 + nt * 16 + l15;
                size_t idx = (ibase + (size_t)(y0 + py) * 256 + x0 + lxx) * 192 + col;
                out[idx] = out[idx] + acc[mt][nt][r] + fc2b[col];
            }
}

// ---------------- host ----------------
extern "C" void kernel_launch(void* const* d_in, const int* in_sizes, int n_in,
                              void* d_out, int out_size, void* d_ws, size_t ws_size,
                              hipStream_t stream) {
    (void)in_sizes; (void)n_in; (void)out_size; (void)ws_size;
    const float* x     = (const float*)d_in[0];
    const float* scale = (const float*)d_in[1];
    const float* n1g   = (const float*)d_in[2];
    const float* n1b   = (const float*)d_in[3];
    const float* qkvw  = (const float*)d_in[4];
    const float* qkvb  = (const float*)d_in[5];
    const float* projw = (const float*)d_in[6];
    const float* projb = (const float*)d_in[7];
    const float* cw1   = (const float*)d_in[8];
    const float* cb1   = (const float*)d_in[9];
    const float* cw2   = (const float*)d_in[10];
    const float* cb2   = (const float*)d_in[11];
    const float* n2g   = (const float*)d_in[12];
    const float* n2b   = (const float*)d_in[13];
    const float* fc1w  = (const float*)d_in[14];
    const float* fc1b  = (const float*)d_in[15];
    const float* fc2w  = (const float*)d_in[16];
    const float* fc2b  = (const float*)d_in[17];
    const float* dww   = (const float*)d_in[18];
    const float* dwb   = (const float*)d_in[19];
    float* out = (float*)d_out;

    char* ws = (char*)d_ws;
    unsigned short* qkvT  = (unsigned short*)ws;       // [576][192]
    unsigned short* projT = qkvT + 110592;             // [192][192]
    unsigned short* fc1T  = projT + 36864;             // [768][192]
    unsigned short* fc2T  = fc1T + 147456;             // [192][768]
    float* btab   = (float*)(ws + 1048576);            // [225][6]
    float* dwwTf  = (float*)(ws + 1310720);            // [9][768] fp32 tap-major
    unsigned short* pool = (unsigned short*)(ws + 4194304);
    const size_t S = 25165824;                          // 50.3MB slots (ushort count)
    unsigned short* qb = pool;
    unsigned short* kb = pool + S;
    unsigned short* vb = pool + 2 * S;
    unsigned short* ab = pool + 3 * S;
    unsigned short* m1 = pool;                          // [2*65536][768] bf16 (201.3MB)

    transpose_w<<<432, 256, 0, stream>>>(qkvw, qkvT, 192, 576);
    transpose_w<<<144, 256, 0, stream>>>(projw, projT, 192, 192);
    transpose_w<<<576, 256, 0, stream>>>(fc1w, fc1T, 192, 768);
    transpose_w<<<576, 256, 0, stream>>>(fc2w, fc2T, 768, 192);
    transpose_wf<<<27, 256, 0, stream>>>(dww, dwwTf, 768, 9);  // dwwTf[tap*768+c]=dww[c*9+tap]
    cpb_kernel<<<1, 256, 0, stream>>>(scale, cw1, cb1, cw2, cb2, btab);

    gemm64<0><<<2048, 512, 0, stream>>>(
        x, (const unsigned short*)nullptr, (const float*)nullptr, n1g, n1b,
        qkvT, qkvb,
        qb, kb, vb, (const float*)nullptr, (float*)nullptr, (unsigned short*)nullptr,
        (float*)nullptr);
    attn_win<<<12288, 64, 0, stream>>>(qb, kb, vb, btab, ab);
    gemm_fused12<<<2048, 512, 0, stream>>>(
        ab, x, projT, projb, fc1T, fc1b, n2g, n2b, out, m1);
    conv_fc2_v14<<<1024, 512, 0, stream>>>(m1, dwwTf, dwb, fc2T, fc2b, out);
}

// Round 22
// 553.192 us; speedup vs baseline: 1.0204x; 1.0204x over previous
//
#include <hip/hip_runtime.h>
#include <hip/hip_bf16.h>

typedef __attribute__((ext_vector_type(8))) short  bf16x8;
typedef __attribute__((ext_vector_type(4))) float  f32x4;
typedef __attribute__((ext_vector_type(8))) unsigned short u16x8;
typedef __attribute__((ext_vector_type(4))) unsigned short u16x4;

__device__ __forceinline__ unsigned short f2b(float f) {
    unsigned int u = __builtin_bit_cast(unsigned int, f);
    u += 0x7FFFu + ((u >> 16) & 1u);
    return (unsigned short)(u >> 16);
}
__device__ __forceinline__ float b2f(unsigned short u) {
    return __builtin_bit_cast(float, (unsigned int)u << 16);
}
// sigmoid-form GELU: x*sigmoid(1.702x). ~5 VALU ops.
__device__ __forceinline__ float gelu_fast(float x) {
    float d = 1.0f + __expf(-1.702f * x);
    return x * __builtin_amdgcn_rcpf(d);
}
// windowed row m -> original row (b*65536 + y*256 + x)
__device__ __forceinline__ int wperm(int m) {
    int w = m >> 6, n = m & 63;
    int b = w >> 10, wy = (w >> 5) & 31, wx = w & 31;
    int y = wy * 8 + (n >> 3), xx = wx * 8 + (n & 7);
    return (b << 16) + (y << 8) + xx;
}

__device__ __forceinline__ void gload_lds16(const void* g, void* l) {
    __builtin_amdgcn_global_load_lds(
        (const __attribute__((address_space(1))) void*)g,
        (__attribute__((address_space(3))) void*)l, 16, 0, 0);
}

// ---------------- prep kernels ----------------
__global__ void transpose_w(const float* __restrict__ in, unsigned short* __restrict__ out,
                            int K, int N) {
    int i = blockIdx.x * 256 + threadIdx.x;
    if (i >= K * N) return;
    int n = i / K, k = i - n * K;
    out[i] = f2b(in[k * N + n]);
}

__global__ void transpose_wf(const float* __restrict__ in, float* __restrict__ out,
                             int K, int N) {
    int i = blockIdx.x * 256 + threadIdx.x;
    if (i >= K * N) return;
    int n = i / K, k = i - n * K;
    out[i] = in[k * N + n];
}

__global__ __launch_bounds__(256) void cpb_kernel(
    const float* __restrict__ scale, const float* __restrict__ w1, const float* __restrict__ b1,
    const float* __restrict__ w2, const float* __restrict__ b2, float* __restrict__ btab) {
    int t = threadIdx.x;
    if (t >= 225) return;
    int i = t / 15, j = t - (t / 15) * 15;
    float ti = (i - 7) * (8.0f / 7.0f);
    float tj = (j - 7) * (8.0f / 7.0f);
    float s0 = scale[0], s1 = scale[1];
    float acc[6];
    #pragma unroll
    for (int h = 0; h < 6; ++h) acc[h] = b2[h];
    for (int k = 0; k < 512; ++k) {
        float hv = ti * w1[k] + tj * w1[512 + k] + s0 * w1[1024 + k] + s1 * w1[1536 + k] + b1[k];
        hv = fmaxf(hv, 0.f);
        #pragma unroll
        for (int h = 0; h < 6; ++h) acc[h] += hv * w2[k * 6 + h];
    }
    #pragma unroll
    for (int h = 0; h < 6; ++h) btab[t * 6 + h] = acc[h];
}

// ---------------- GEMM: M-tile 64, full-K A-panel in LDS, 8 waves ----------
// MODE 0 only: A = LN1(x[wperm]) in-block -> q/k/v scatter (q scaled).
template<int MODE>
__global__ __launch_bounds__(512) void gemm64(
    const float* __restrict__ Af,
    const float* __restrict__ lng, const float* __restrict__ lnb,
    const unsigned short* __restrict__ Bt, const float* __restrict__ bias,
    unsigned short* __restrict__ oq, unsigned short* __restrict__ ok2, unsigned short* __restrict__ ov) {
    constexpr int NCT = 3;
    __shared__ __align__(16) unsigned short Asw[3 * 64 * 64];    // 24576 B
    __shared__ __align__(16) unsigned short Bsw[2 * 192 * 64];   // 49152 B
    const int t = threadIdx.x, lane = t & 63, wv8 = t >> 6;
    const int wm = wv8 >> 2, wn = wv8 & 3;           // 2m x 4n
    const int l15 = lane & 15, lq = lane >> 4;
    const int m0 = blockIdx.x * 64;

    int boffs[3];
    #pragma unroll
    for (int s = 0; s < 3; ++s) {
        int row = (wv8 + 8 * s) * 8 + (lane >> 3);
        boffs[s] = row * 192 + ((lane & 7) ^ (lane >> 3)) * 8;
    }
    #pragma unroll
    for (int s = 0; s < 3; ++s)   // B (ct0, k0) -> buf 0
        gload_lds16(Bt + boffs[s], (char*)Bsw + (wv8 + 8 * s) * 1024);

    {   // LN1 in-block: 8 lanes per row, 24 elems each
        int row = t >> 3, oct = t & 7;
        const float* p = Af + (size_t)wperm(m0 + row) * 192 + oct * 24;
        f32x4 v[6];
        float s = 0.f, q = 0.f;
        #pragma unroll
        for (int i = 0; i < 6; ++i) {
            v[i] = *(const f32x4*)(p + i * 4);
            #pragma unroll
            for (int j = 0; j < 4; ++j) { s += v[i][j]; q += v[i][j] * v[i][j]; }
        }
        s += __shfl_xor(s, 1); s += __shfl_xor(s, 2); s += __shfl_xor(s, 4);
        q += __shfl_xor(q, 1); q += __shfl_xor(q, 2); q += __shfl_xor(q, 4);
        float mean = s * (1.f / 192.f);
        float rstd = rsqrtf(q * (1.f / 192.f) - mean * mean + 1e-5f);
        #pragma unroll
        for (int i = 0; i < 6; ++i) {
            int k = oct * 24 + i * 4;
            u16x4 pk;
            #pragma unroll
            for (int j = 0; j < 4; ++j)
                pk[j] = f2b((v[i][j] - mean) * rstd * lng[k + j] + lnb[k + j]);
            int cc = k >> 6, ch = (k >> 2) & 15;
            int byte = cc * 8192 + row * 128 +
                       ((((ch >> 1) ^ (row & 7)) << 4) + ((ch & 1) << 3));
            *(u16x4*)((char*)Asw + byte) = pk;
        }
        asm volatile("s_waitcnt lgkmcnt(0)" ::: "memory");
    }

    const int axor = (l15 & 7) << 4;
    int cur = 0, it = 0;
    for (int ct = 0; ct < NCT; ++ct) {
        f32x4 acc[2][3];
        #pragma unroll
        for (int i = 0; i < 2; ++i)
            #pragma unroll
            for (int j = 0; j < 3; ++j) acc[i][j] = (f32x4){0.f, 0.f, 0.f, 0.f};
        for (int c = 0; c < 3; ++c, ++it) {
            if (it < NCT * 3 - 1) {
                int ctn = (c == 2) ? ct + 1 : ct;
                int cn  = (c == 2) ? 0 : c + 1;
                #pragma unroll
                for (int s = 0; s < 3; ++s)
                    gload_lds16(Bt + (size_t)ctn * 36864 + boffs[s] + cn * 64,
                                (char*)Bsw + (cur ^ 1) * 24576 + (wv8 + 8 * s) * 1024);
                asm volatile("s_waitcnt vmcnt(3)" ::: "memory");
            } else {
                asm volatile("s_waitcnt vmcnt(0)" ::: "memory");
            }
            __builtin_amdgcn_sched_barrier(0);
            __builtin_amdgcn_s_barrier();
            __builtin_amdgcn_sched_barrier(0);
            const char* Al = (const char*)Asw + c * 8192;
            const char* Bl = (const char*)Bsw + cur * 24576;
            #pragma unroll
            for (int kk = 0; kk < 2; ++kk) {
                bf16x8 a[2], bb[3];
                #pragma unroll
                for (int mt = 0; mt < 2; ++mt)
                    a[mt] = *(const bf16x8*)(Al + (wm * 32 + mt * 16 + l15) * 128 +
                                             ((kk << 6) ^ (lq << 4) ^ axor));
                #pragma unroll
                for (int nt = 0; nt < 3; ++nt)
                    bb[nt] = *(const bf16x8*)(Bl + (wn * 48 + nt * 16 + l15) * 128 +
                                              ((kk << 6) ^ (lq << 4) ^ axor));
                #pragma unroll
                for (int mt = 0; mt < 2; ++mt)
                    #pragma unroll
                    for (int nt = 0; nt < 3; ++nt)
                        acc[mt][nt] = __builtin_amdgcn_mfma_f32_16x16x32_bf16(a[mt], bb[nt], acc[mt][nt], 0, 0, 0);
            }
            __builtin_amdgcn_sched_barrier(0);
            __builtin_amdgcn_s_barrier();
            cur ^= 1;
        }
        unsigned short* dst = (ct == 0) ? oq : (ct == 1) ? ok2 : ov;
        float qs = (ct == 0) ? 0.17677669529663689f : 1.0f;
        #pragma unroll
        for (int mt = 0; mt < 2; ++mt)
            #pragma unroll
            for (int nt = 0; nt < 3; ++nt)
                #pragma unroll
                for (int r = 0; r < 4; ++r) {
                    int m = m0 + wm * 32 + mt * 16 + lq * 4 + r;
                    int col = wn * 48 + nt * 16 + l15;
                    float v = (acc[mt][nt][r] + bias[ct * 192 + col]) * qs;
                    int head = col >> 5, d = col & 31;
                    int w = m >> 6, n = m & 63;
                    dst[((size_t)(w * 6 + head) * 64 + n) * 32 + d] = f2b(v);
                }
    }
}

// ---- fused: windowed attention + proj + residual + LN2 + fc1 + gelu -------
// Block = one window (M-tile 64 = exactly the window's 64 tokens).
// Phase 0: waves 0..5 = heads. vT (swz [32][64]) in Asw+h*4096; P (swz
// [64][64]) in Bsw+h*8192; QK->softmax->PV per attn_win math. O held in regs.
// Then O written directly into the swizzled A panel (identical layout to the
// gload-staged panel). Phase 1: proj (+residual, +LN2 stats/normalize in-block,
// values held in regs). Phase 2: fc1 + gelu -> m1. Eliminates attn_win launch,
// the ab buffer round-trip (100MB), and q/k/v re-staging.
__global__ __launch_bounds__(512) void attn_proj_fc1(
    const unsigned short* __restrict__ qb, const unsigned short* __restrict__ kb,
    const unsigned short* __restrict__ vb, const float* __restrict__ btab,
    const float* __restrict__ resid,
    const unsigned short* __restrict__ projT, const float* __restrict__ projb,
    const unsigned short* __restrict__ fc1T, const float* __restrict__ fc1b,
    const float* __restrict__ n2g, const float* __restrict__ n2b,
    float* __restrict__ ofp, unsigned short* __restrict__ obf) {
    __shared__ __align__(16) unsigned short Asw[3 * 64 * 64];    // 24576 B
    __shared__ __align__(16) unsigned short Bsw[2 * 192 * 64];   // 49152 B
    __shared__ float scratch[1352];                              // sbias | sred+srow
    const int t = threadIdx.x, lane = t & 63, wv8 = t >> 6;
    const int wm = wv8 >> 2, wn = wv8 & 3;
    const int l15 = lane & 15, lq = lane >> 4;
    const int win = blockIdx.x;
    const int m0 = win * 64;
    const int axor = (l15 & 7) << 4;

    // stage per-head bias tables: sbias[h*225+idx] = btab[idx*6+h]
    for (int i = t; i < 1350; i += 512) {
        int h = i / 225, idx = i - h * 225;
        scratch[i] = btab[idx * 6 + h];
    }
    __syncthreads();

    f32x4 o[4][2];
    // ---------------- phase 0: attention (waves 0..5) ----------------
    if (wv8 < 6) {
        const size_t bid = (size_t)(win * 6 + wv8);
        const unsigned short* qp = qb + bid * 2048;
        const unsigned short* kp = kb + bid * 2048;
        const unsigned short* vp = vb + bid * 2048;
        bf16x8 qf[4], kf[4];
        #pragma unroll
        for (int i = 0; i < 4; ++i) {
            qf[i] = *(const bf16x8*)(qp + (i * 16 + l15) * 32 + lq * 8);
            kf[i] = *(const bf16x8*)(kp + (i * 16 + l15) * 32 + lq * 8);
        }
        #pragma unroll
        for (int i = 0; i < 4; ++i) {   // V^T into Asw+h*4096 (swz [32 d][64 m])
            int c = lane + i * 64;
            int mr = c >> 2, d0 = (c & 3) * 8;
            u16x8 v = *(const u16x8*)(vp + mr * 32 + d0);
            #pragma unroll
            for (int j = 0; j < 8; ++j) {
                int row = d0 + j;
                int byte = wv8 * 4096 + row * 128 +
                           (((mr >> 3) ^ (row & 7)) << 4) + (mr & 7) * 2;
                *(unsigned short*)((char*)Asw + byte) = v[j];
            }
        }
        #pragma unroll
        for (int mt = 0; mt < 4; ++mt) {    // QK + softmax per mt (low reg)
            f32x4 s[4];
            #pragma unroll
            for (int nt = 0; nt < 4; ++nt)
                s[nt] = __builtin_amdgcn_mfma_f32_16x16x32_bf16(
                    qf[mt], kf[nt], (f32x4){0.f, 0.f, 0.f, 0.f}, 0, 0, 0);
            #pragma unroll
            for (int r = 0; r < 4; ++r) {
                int n = mt * 16 + lq * 4 + r;
                int ny = n >> 3, nx = n & 7;
                float sv[4];
                float mx = -1e30f;
                #pragma unroll
                for (int nt = 0; nt < 4; ++nt) {
                    int m = nt * 16 + l15;
                    int idx = (ny - (m >> 3) + 7) * 15 + (nx - (m & 7) + 7);
                    float val = s[nt][r] + scratch[wv8 * 225 + idx];
                    sv[nt] = val;
                    mx = fmaxf(mx, val);
                }
                #pragma unroll
                for (int off = 1; off < 16; off <<= 1) mx = fmaxf(mx, __shfl_xor(mx, off));
                float sum = 0.f;
                #pragma unroll
                for (int nt = 0; nt < 4; ++nt) { sv[nt] = __expf(sv[nt] - mx); sum += sv[nt]; }
                #pragma unroll
                for (int off = 1; off < 16; off <<= 1) sum += __shfl_xor(sum, off);
                float inv = 1.f / sum;
                #pragma unroll
                for (int nt = 0; nt < 4; ++nt) {
                    int col = nt * 16 + l15;
                    int byte = wv8 * 8192 + n * 128 +
                               (((col >> 3) ^ (n & 7)) << 4) + (col & 7) * 2;
                    *(unsigned short*)((char*)Bsw + byte) = f2b(sv[nt] * inv);
                }
            }
        }
        asm volatile("s_waitcnt lgkmcnt(0)" ::: "memory");
        #pragma unroll
        for (int i = 0; i < 4; ++i)
            #pragma unroll
            for (int j = 0; j < 2; ++j) o[i][j] = (f32x4){0.f, 0.f, 0.f, 0.f};
        #pragma unroll
        for (int mt = 0; mt < 4; ++mt)
            #pragma unroll
            for (int kk = 0; kk < 2; ++kk) {
                bf16x8 a = *(const bf16x8*)((char*)Bsw + wv8 * 8192 +
                    (mt * 16 + l15) * 128 + ((kk << 6) ^ (lq << 4) ^ axor));
                #pragma unroll
                for (int dt = 0; dt < 2; ++dt) {
                    bf16x8 b = *(const bf16x8*)((char*)Asw + wv8 * 4096 +
                        (dt * 16 + l15) * 128 + ((kk << 6) ^ (lq << 4) ^ axor));
                    o[mt][dt] = __builtin_amdgcn_mfma_f32_16x16x32_bf16(a, b, o[mt][dt], 0, 0, 0);
                }
            }
    }
    __syncthreads();   // attention done; Asw/Bsw free
    if (wv8 < 6) {     // O -> swizzled A panel (cols wv8*32..+32)
        #pragma unroll
        for (int mt = 0; mt < 4; ++mt)
            #pragma unroll
            for (int dt = 0; dt < 2; ++dt)
                #pragma unroll
                for (int r = 0; r < 4; ++r) {
                    int row = mt * 16 + lq * 4 + r;
                    int k = wv8 * 32 + dt * 16 + l15;
                    int cc = k >> 6, k6 = k & 63;
                    int byte = cc * 8192 + row * 128 +
                               (((k6 >> 3) ^ (row & 7)) << 4) + (k6 & 7) * 2;
                    *(unsigned short*)((char*)Asw + byte) = f2b(o[mt][dt][r]);
                }
    }
    int boffs[3];
    #pragma unroll
    for (int s = 0; s < 3; ++s) {
        int row = (wv8 + 8 * s) * 8 + (lane >> 3);
        boffs[s] = row * 192 + ((lane & 7) ^ (lane >> 3)) * 8;
    }
    #pragma unroll
    for (int s = 0; s < 3; ++s)     // proj B chunk 0 -> buf 0
        gload_lds16(projT + boffs[s], (char*)Bsw + (wv8 + 8 * s) * 1024);
    __syncthreads();                // A panel ready; B chunk0 ready (drained)

    int cur = 0;
    // ---------------- phase 1: proj ----------------
    f32x4 acc[2][3];
    #pragma unroll
    for (int i = 0; i < 2; ++i)
        #pragma unroll
        for (int j = 0; j < 3; ++j) acc[i][j] = (f32x4){0.f, 0.f, 0.f, 0.f};
    for (int c = 0; c < 3; ++c) {
        if (c < 2) {
            #pragma unroll
            for (int s = 0; s < 3; ++s)
                gload_lds16(projT + boffs[s] + (c + 1) * 64,
                            (char*)Bsw + (cur ^ 1) * 24576 + (wv8 + 8 * s) * 1024);
        } else {   // prefetch fc1 ct0 chunk0 (lands during epilogue)
            #pragma unroll
            for (int s = 0; s < 3; ++s)
                gload_lds16(fc1T + boffs[s],
                            (char*)Bsw + (cur ^ 1) * 24576 + (wv8 + 8 * s) * 1024);
        }
        asm volatile("s_waitcnt vmcnt(3)" ::: "memory");
        __builtin_amdgcn_sched_barrier(0);
        __builtin_amdgcn_s_barrier();
        __builtin_amdgcn_sched_barrier(0);
        const char* Al = (const char*)Asw + c * 8192;
        const char* Bl = (const char*)Bsw + cur * 24576;
        #pragma unroll
        for (int kk = 0; kk < 2; ++kk) {
            bf16x8 a[2], bb[3];
            #pragma unroll
            for (int mt = 0; mt < 2; ++mt)
                a[mt] = *(const bf16x8*)(Al + (wm * 32 + mt * 16 + l15) * 128 +
                                         ((kk << 6) ^ (lq << 4) ^ axor));
            #pragma unroll
            for (int nt = 0; nt < 3; ++nt)
                bb[nt] = *(const bf16x8*)(Bl + (wn * 48 + nt * 16 + l15) * 128 +
                                          ((kk << 6) ^ (lq << 4) ^ axor));
            #pragma unroll
            for (int mt = 0; mt < 2; ++mt)
                #pragma unroll
                for (int nt = 0; nt < 3; ++nt)
                    acc[mt][nt] = __builtin_amdgcn_mfma_f32_16x16x32_bf16(a[mt], bb[nt], acc[mt][nt], 0, 0, 0);
        }
        __builtin_amdgcn_sched_barrier(0);
        __builtin_amdgcn_s_barrier();
        cur ^= 1;
    }
    // ---- epilogue 1: out write + stats (values held in regs) ----
    float* sred = scratch;          // [64][8]
    float* srow = scratch + 512;    // [64][2]
    float hw[2][3][4];
    #pragma unroll
    for (int mt = 0; mt < 2; ++mt) {
        #pragma unroll
        for (int r = 0; r < 4; ++r) {
            int row = wm * 32 + mt * 16 + lq * 4 + r;
            int r2 = wperm(m0 + row);
            float s = 0.f, q = 0.f;
            #pragma unroll
            for (int nt = 0; nt < 3; ++nt) {
                int col = wn * 48 + nt * 16 + l15;
                size_t idx = (size_t)r2 * 192 + col;
                float wv = resid[idx] + acc[mt][nt][r] + projb[col];
                ofp[idx] = wv;
                hw[mt][nt][r] = wv;
                s += wv;
                q += wv * wv;
            }
            #pragma unroll
            for (int off = 1; off < 16; off <<= 1) {
                s += __shfl_xor(s, off);
                q += __shfl_xor(q, off);
            }
            if (l15 == 0) {
                sred[row * 8 + wn * 2]     = s;
                sred[row * 8 + wn * 2 + 1] = q;
            }
        }
    }
    __syncthreads();
    if (t < 64) {
        float s = sred[t * 8] + sred[t * 8 + 2] + sred[t * 8 + 4] + sred[t * 8 + 6];
        float q = sred[t * 8 + 1] + sred[t * 8 + 3] + sred[t * 8 + 5] + sred[t * 8 + 7];
        float mean = s * (1.f / 192.f);
        float var = q * (1.f / 192.f) - mean * mean;
        srow[t * 2] = mean;
        srow[t * 2 + 1] = rsqrtf(var + 1e-5f);
    }
    __syncthreads();
    {   // normalize held values into swizzled Asw panel
        float g3[3], b3[3];
        #pragma unroll
        for (int nt = 0; nt < 3; ++nt) {
            int col = wn * 48 + nt * 16 + l15;
            g3[nt] = n2g[col];
            b3[nt] = n2b[col];
        }
        #pragma unroll
        for (int mt = 0; mt < 2; ++mt)
            #pragma unroll
            for (int r = 0; r < 4; ++r) {
                int row = wm * 32 + mt * 16 + lq * 4 + r;
                float mean = srow[row * 2], rstd = srow[row * 2 + 1];
                #pragma unroll
                for (int nt = 0; nt < 3; ++nt) {
                    int k = wn * 48 + nt * 16 + l15;
                    float nv = (hw[mt][nt][r] - mean) * rstd * g3[nt] + b3[nt];
                    int cc = k >> 6, k6 = k & 63;
                    int byte = cc * 8192 + row * 128 +
                               (((k6 >> 3) ^ (row & 7)) << 4) + (k6 & 7) * 2;
                    *(unsigned short*)((char*)Asw + byte) = f2b(nv);
                }
            }
    }
    __syncthreads();   // A panel ready (fc1 ct0c0 prefetch also drained)

    // ---------------- phase 2: fc1, NCT = 4 ----------------
    for (int ct = 0; ct < 4; ++ct) {
        f32x4 a2[2][3];
        #pragma unroll
        for (int i = 0; i < 2; ++i)
            #pragma unroll
            for (int j = 0; j < 3; ++j) a2[i][j] = (f32x4){0.f, 0.f, 0.f, 0.f};
        for (int c = 0; c < 3; ++c) {
            int it = ct * 3 + c;
            if (it < 11) {
                int ctn = (c == 2) ? ct + 1 : ct;
                int cn  = (c == 2) ? 0 : c + 1;
                #pragma unroll
                for (int s = 0; s < 3; ++s)
                    gload_lds16(fc1T + (size_t)ctn * 36864 + boffs[s] + cn * 64,
                                (char*)Bsw + (cur ^ 1) * 24576 + (wv8 + 8 * s) * 1024);
                asm volatile("s_waitcnt vmcnt(3)" ::: "memory");
            } else {
                asm volatile("s_waitcnt vmcnt(0)" ::: "memory");
            }
            __builtin_amdgcn_sched_barrier(0);
            __builtin_amdgcn_s_barrier();
            __builtin_amdgcn_sched_barrier(0);
            const char* Al = (const char*)Asw + c * 8192;
            const char* Bl = (const char*)Bsw + cur * 24576;
            #pragma unroll
            for (int kk = 0; kk < 2; ++kk) {
                bf16x8 a[2], bb[3];
                #pragma unroll
                for (int mt = 0; mt < 2; ++mt)
                    a[mt] = *(const bf16x8*)(Al + (wm * 32 + mt * 16 + l15) * 128 +
                                             ((kk << 6) ^ (lq << 4) ^ axor));
                #pragma unroll
                for (int nt = 0; nt < 3; ++nt)
                    bb[nt] = *(const bf16x8*)(Bl + (wn * 48 + nt * 16 + l15) * 128 +
                                              ((kk << 6) ^ (lq << 4) ^ axor));
                #pragma unroll
                for (int mt = 0; mt < 2; ++mt)
                    #pragma unroll
                    for (int nt = 0; nt < 3; ++nt)
                        a2[mt][nt] = __builtin_amdgcn_mfma_f32_16x16x32_bf16(a[mt], bb[nt], a2[mt][nt], 0, 0, 0);
            }
            __builtin_amdgcn_sched_barrier(0);
            __builtin_amdgcn_s_barrier();
            cur ^= 1;
        }
        #pragma unroll
        for (int mt = 0; mt < 2; ++mt)
            #pragma unroll
            for (int nt = 0; nt < 3; ++nt)
                #pragma unroll
                for (int r = 0; r < 4; ++r) {
                    int m = m0 + wm * 32 + mt * 16 + lq * 4 + r;
                    int col = wn * 48 + nt * 16 + l15;
                    obf[(size_t)wperm(m) * 768 + ct * 192 + col] =
                        f2b(gelu_fast(a2[mt][nt][r] + fc1b[ct * 192 + col]));
                }
    }
}

// -------- fused depthwise 3x3 conv + gelu + fc2 + residual ------------------
// v14 (proven 199us): tile 32x*4y, vertical-pair threads share tap weights.
__global__ __launch_bounds__(512) void conv_fc2_v14(
    const unsigned short* __restrict__ m1, const float* __restrict__ dwwTf,
    const float* __restrict__ dwb, const unsigned short* __restrict__ fc2T,
    const float* __restrict__ fc2b, float* __restrict__ out) {
    __shared__ __align__(16) unsigned short Xs[26 * 512];      // 26624 B (13056 used)
    __shared__ __align__(16) unsigned short As[128 * 72];      // 18432 B
    __shared__ __align__(16) unsigned short Bsw[192 * 64];     // 24576 B
    const int t = threadIdx.x;
    const int g = ((blockIdx.x & 7) << 7) + (blockIdx.x >> 3); // 1024 blocks, XCD bands
    const int b = g >> 9, yt = (g >> 3) & 63, xq = g & 7;
    const int y0 = yt * 4, x0 = xq * 32;
    const int cg = t & 7, lx = t >> 3;               // lx in [0,64)
    const int xx = lx & 31, yy0 = lx >> 5;           // output rows yy0, yy0+2
    const size_t ibase = (size_t)b * 65536;

    const int lane = t & 63, wv8 = t >> 6;           // wave 0..7
    const int wm = wv8 >> 1, wn = wv8 & 1;           // 4m x 2n wave grid
    const int l15 = lane & 15, lq = lane >> 4;

    int xoff[4];
    #pragma unroll
    for (int s = 0; s < 4; ++s) {
        int seg = wv8 + 8 * s;
        int e = seg * 512 + lane * 8;
        e = min(e, 13048);
        int row = e / 2176;
        int rem = e - row * 2176;
        int px = rem >> 6, ch = rem & 63;
        int gy = min(max(y0 - 1 + row, 0), 255);
        int gx = min(max(x0 - 1 + px, 0), 255);
        xoff[s] = ((b << 16) + (gy << 8) + gx) * 768 + ch;
    }
    int boff[3];
    #pragma unroll
    for (int s = 0; s < 3; ++s) {
        int row = (wv8 + 8 * s) * 8 + (lane >> 3);
        boff[s] = row * 768 + ((lane & 7) ^ (lane >> 3)) * 8;
    }

    f32x4 acc[2][6];
    #pragma unroll
    for (int i = 0; i < 2; ++i)
        #pragma unroll
        for (int j = 0; j < 6; ++j) acc[i][j] = (f32x4){0.f, 0.f, 0.f, 0.f};

    #pragma unroll
    for (int s = 0; s < 4; ++s)
        if (wv8 + 8 * s < 26)
            gload_lds16(m1 + xoff[s], (char*)Xs + (wv8 + 8 * s) * 1024);
    #pragma unroll
    for (int s = 0; s < 3; ++s)
        gload_lds16(fc2T + boff[s], (char*)Bsw + (wv8 + 8 * s) * 1024);

    const int xb = xx * 128 + cg * 16;
    const int gxp = x0 + xx;
    const bool xok0 = gxp >= 1;
    const bool xok2 = gxp <= 254;
    const int oy0 = y0 + yy0;
    const int o00 = (lq * 16) ^ ((l15 & 7) << 4);
    const int brow = (wn * 96 + l15) * 128;

    for (int k0 = 0; k0 < 768; k0 += 64) {
        const int c0 = k0 + cg * 8;
        asm volatile("s_waitcnt vmcnt(0)" ::: "memory");
        __syncthreads();                               // b1: Xs,Bsw ready
        float a0[8], a1[8];
        #pragma unroll
        for (int j = 0; j < 8; ++j) { a0[j] = 0.f; a1[j] = 0.f; }
        #pragma unroll
        for (int kx = 0; kx < 3; ++kx) {
            if (kx == 0 && !xok0) continue;
            if (kx == 2 && !xok2) continue;
            #pragma unroll
            for (int ky = 0; ky < 3; ++ky) {
                const float* wp = dwwTf + (ky * 3 + kx) * 768 + c0;
                f32x4 w0 = *(const f32x4*)wp;
                f32x4 w1 = *(const f32x4*)(wp + 4);
                if ((unsigned)(oy0 + ky - 1) < 256u) {
                    u16x8 in = *(const u16x8*)((const char*)Xs +
                        (yy0 + ky) * 4352 + xb + kx * 128);
                    #pragma unroll
                    for (int j = 0; j < 4; ++j) {
                        a0[j]     += b2f(in[j]) * w0[j];
                        a0[4 + j] += b2f(in[4 + j]) * w1[j];
                    }
                }
                if ((unsigned)(oy0 + ky + 1) < 256u) {
                    u16x8 in = *(const u16x8*)((const char*)Xs +
                        (yy0 + 2 + ky) * 4352 + xb + kx * 128);
                    #pragma unroll
                    for (int j = 0; j < 4; ++j) {
                        a1[j]     += b2f(in[j]) * w0[j];
                        a1[4 + j] += b2f(in[4 + j]) * w1[j];
                    }
                }
            }
        }
        {
            f32x4 b0 = *(const f32x4*)(dwb + c0);
            f32x4 b1 = *(const f32x4*)(dwb + c0 + 4);
            u16x8 o0, o1;
            #pragma unroll
            for (int j = 0; j < 4; ++j) {
                o0[j]     = f2b(gelu_fast(a0[j] + b0[j]));
                o0[4 + j] = f2b(gelu_fast(a0[4 + j] + b1[j]));
                o1[j]     = f2b(gelu_fast(a1[j] + b0[j]));
                o1[4 + j] = f2b(gelu_fast(a1[4 + j] + b1[j]));
            }
            *(u16x8*)&As[lx * 72 + cg * 8] = o0;
            *(u16x8*)&As[(lx + 64) * 72 + cg * 8] = o1;
        }
        __syncthreads();                               // b2: As ready, Xs free
        if (k0 < 704) {
            #pragma unroll
            for (int s = 0; s < 4; ++s)
                if (wv8 + 8 * s < 26)
                    gload_lds16(m1 + xoff[s] + k0 + 64,
                                (char*)Xs + (wv8 + 8 * s) * 1024);
        }
        #pragma unroll
        for (int kk = 0; kk < 2; ++kk) {
            bf16x8 af[2];
            #pragma unroll
            for (int mt = 0; mt < 2; ++mt)
                af[mt] = *(bf16x8*)&As[(wm * 32 + mt * 16 + l15) * 72 + kk * 32 + lq * 8];
            #pragma unroll
            for (int nt = 0; nt < 6; ++nt) {
                bf16x8 bb = *(const bf16x8*)((const char*)Bsw + brow + nt * 2048 + (o00 ^ (kk << 6)));
                #pragma unroll
                for (int mt = 0; mt < 2; ++mt)
                    acc[mt][nt] = __builtin_amdgcn_mfma_f32_16x16x32_bf16(af[mt], bb, acc[mt][nt], 0, 0, 0);
            }
        }
        __syncthreads();                               // b3: As,Bsw free
        if (k0 < 704) {
            #pragma unroll
            for (int s = 0; s < 3; ++s)
                gload_lds16(fc2T + boff[s] + k0 + 64, (char*)Bsw + (wv8 + 8 * s) * 1024);
        }
    }
    #pragma unroll
    for (int mt = 0; mt < 2; ++mt)
        #pragma unroll
        for (int nt = 0; nt < 6; ++nt)
            #pragma unroll
            for (int r = 0; r < 4; ++r) {
                int ml = wm * 32 + mt * 16 + lq * 4 + r;
                int py = ml >> 5, lxx = ml & 31;
                int col = wn * 96 + nt * 16 + l15;
                size_t idx = (ibase + (size_t)(y0 + py) * 256 + x0 + lxx) * 192 + col;
                out[idx] = out[idx] + acc[mt][nt][r] + fc2b[col];
            }
}

// ---------------- host ----------------
extern "C" void kernel_launch(void* const* d_in, const int* in_sizes, int n_in,
                              void* d_out, int out_size, void* d_ws, size_t ws_size,
                              hipStream_t stream) {
    (void)in_sizes; (void)n_in; (void)out_size; (void)ws_size;
    const float* x     = (const float*)d_in[0];
    const float* scale = (const float*)d_in[1];
    const float* n1g   = (const float*)d_in[2];
    const float* n1b   = (const float*)d_in[3];
    const float* qkvw  = (const float*)d_in[4];
    const float* qkvb  = (const float*)d_in[5];
    const float* projw = (const float*)d_in[6];
    const float* projb = (const float*)d_in[7];
    const float* cw1   = (const float*)d_in[8];
    const float* cb1   = (const float*)d_in[9];
    const float* cw2   = (const float*)d_in[10];
    const float* cb2   = (const float*)d_in[11];
    const float* n2g   = (const float*)d_in[12];
    const float* n2b   = (const float*)d_in[13];
    const float* fc1w  = (const float*)d_in[14];
    const float* fc1b  = (const float*)d_in[15];
    const float* fc2w  = (const float*)d_in[16];
    const float* fc2b  = (const float*)d_in[17];
    const float* dww   = (const float*)d_in[18];
    const float* dwb   = (const float*)d_in[19];
    float* out = (float*)d_out;

    char* ws = (char*)d_ws;
    unsigned short* qkvT  = (unsigned short*)ws;       // [576][192]
    unsigned short* projT = qkvT + 110592;             // [192][192]
    unsigned short* fc1T  = projT + 36864;             // [768][192]
    unsigned short* fc2T  = fc1T + 147456;             // [192][768]
    float* btab   = (float*)(ws + 1048576);            // [225][6]
    float* dwwTf  = (float*)(ws + 1310720);            // [9][768] fp32 tap-major
    unsigned short* pool = (unsigned short*)(ws + 4194304);
    const size_t S = 25165824;                          // 50.3MB slots (ushort count)
    unsigned short* qb = pool;
    unsigned short* kb = pool + S;
    unsigned short* vb = pool + 2 * S;
    unsigned short* m1 = pool + 3 * S;                  // [2*65536][768] bf16

    transpose_w<<<432, 256, 0, stream>>>(qkvw, qkvT, 192, 576);
    transpose_w<<<144, 256, 0, stream>>>(projw, projT, 192, 192);
    transpose_w<<<576, 256, 0, stream>>>(fc1w, fc1T, 192, 768);
    transpose_w<<<576, 256, 0, stream>>>(fc2w, fc2T, 768, 192);
    transpose_wf<<<27, 256, 0, stream>>>(dww, dwwTf, 768, 9);  // dwwTf[tap*768+c]=dww[c*9+tap]
    cpb_kernel<<<1, 256, 0, stream>>>(scale, cw1, cb1, cw2, cb2, btab);

    gemm64<0><<<2048, 512, 0, stream>>>(x, n1g, n1b, qkvT, qkvb, qb, kb, vb);
    attn_proj_fc1<<<2048, 512, 0, stream>>>(
        qb, kb, vb, btab, x, projT, projb, fc1T, fc1b, n2g, n2b, out, m1);
    conv_fc2_v14<<<1024, 512, 0, stream>>>(m1, dwwTf, dwb, fc2T, fc2b, out);
}

// Round 23
// 532.454 us; speedup vs baseline: 1.0602x; 1.0389x over previous
//
#include <hip/hip_runtime.h>
#include <hip/hip_bf16.h>

typedef __attribute__((ext_vector_type(8))) short  bf16x8;
typedef __attribute__((ext_vector_type(4))) float  f32x4;
typedef __attribute__((ext_vector_type(8))) unsigned short u16x8;
typedef __attribute__((ext_vector_type(4))) unsigned short u16x4;

__device__ __forceinline__ unsigned short f2b(float f) {
    unsigned int u = __builtin_bit_cast(unsigned int, f);
    u += 0x7FFFu + ((u >> 16) & 1u);
    return (unsigned short)(u >> 16);
}
__device__ __forceinline__ float b2f(unsigned short u) {
    return __builtin_bit_cast(float, (unsigned int)u << 16);
}
// sigmoid-form GELU: x*sigmoid(1.702x). ~5 VALU ops.
__device__ __forceinline__ float gelu_fast(float x) {
    float d = 1.0f + __expf(-1.702f * x);
    return x * __builtin_amdgcn_rcpf(d);
}
// windowed row m -> original row (b*65536 + y*256 + x)
__device__ __forceinline__ int wperm(int m) {
    int w = m >> 6, n = m & 63;
    int b = w >> 10, wy = (w >> 5) & 31, wx = w & 31;
    int y = wy * 8 + (n >> 3), xx = wx * 8 + (n & 7);
    return (b << 16) + (y << 8) + xx;
}

__device__ __forceinline__ void gload_lds16(const void* g, void* l) {
    __builtin_amdgcn_global_load_lds(
        (const __attribute__((address_space(1))) void*)g,
        (__attribute__((address_space(3))) void*)l, 16, 0, 0);
}

// ---------------- consolidated prep: all transposes + cpb in ONE launch -----
__global__ __launch_bounds__(256) void prep_all(
    const float* __restrict__ qkvw, const float* __restrict__ projw,
    const float* __restrict__ fc1w, const float* __restrict__ fc2w,
    const float* __restrict__ dww,
    unsigned short* __restrict__ qkvT, unsigned short* __restrict__ projT,
    unsigned short* __restrict__ fc1T, unsigned short* __restrict__ fc2T,
    float* __restrict__ dwwTf,
    const float* __restrict__ scale, const float* __restrict__ w1,
    const float* __restrict__ b1, const float* __restrict__ w2,
    const float* __restrict__ b2, float* __restrict__ btab) {
    const int bid = blockIdx.x, t = threadIdx.x;
    if (bid < 432) {                       // qkvT [576n][192k]
        int i = bid * 256 + t;
        int n = i / 192, k = i - n * 192;
        qkvT[i] = f2b(qkvw[k * 576 + n]);
    } else if (bid < 576) {                // projT [192n][192k]
        int i = (bid - 432) * 256 + t;
        int n = i / 192, k = i - n * 192;
        projT[i] = f2b(projw[k * 192 + n]);
    } else if (bid < 1152) {               // fc1T [768n][192k]
        int i = (bid - 576) * 256 + t;
        int n = i / 192, k = i - n * 192;
        fc1T[i] = f2b(fc1w[k * 768 + n]);
    } else if (bid < 1728) {               // fc2T [192n][768k]
        int i = (bid - 1152) * 256 + t;
        int n = i / 768, k = i - n * 768;
        fc2T[i] = f2b(fc2w[k * 192 + n]);
    } else if (bid < 1755) {               // dwwTf [9 tap][768 ch] fp32
        int i = (bid - 1728) * 256 + t;
        if (i < 6912) {
            int n = i / 768, k = i - n * 768;
            dwwTf[i] = dww[k * 9 + n];
        }
    } else {                               // cpb bias table (225 threads)
        if (t >= 225) return;
        int i = t / 15, j = t - (t / 15) * 15;
        float ti = (i - 7) * (8.0f / 7.0f);
        float tj = (j - 7) * (8.0f / 7.0f);
        float s0 = scale[0], s1 = scale[1];
        float acc[6];
        #pragma unroll
        for (int h = 0; h < 6; ++h) acc[h] = b2[h];
        for (int k = 0; k < 512; ++k) {
            float hv = ti * w1[k] + tj * w1[512 + k] + s0 * w1[1024 + k] + s1 * w1[1536 + k] + b1[k];
            hv = fmaxf(hv, 0.f);
            #pragma unroll
            for (int h = 0; h < 6; ++h) acc[h] += hv * w2[k * 6 + h];
        }
        #pragma unroll
        for (int h = 0; h < 6; ++h) btab[t * 6 + h] = acc[h];
    }
}

// ---------------- GEMM: M-tile 64, full-K A-panel in LDS, 8 waves ----------
// MODE 0 only: A = LN1(x[wperm]) in-block -> q/k/v scatter (q scaled).
template<int MODE>
__global__ __launch_bounds__(512) void gemm64(
    const float* __restrict__ Af,
    const float* __restrict__ lng, const float* __restrict__ lnb,
    const unsigned short* __restrict__ Bt, const float* __restrict__ bias,
    unsigned short* __restrict__ oq, unsigned short* __restrict__ ok2, unsigned short* __restrict__ ov) {
    constexpr int NCT = 3;
    __shared__ __align__(16) unsigned short Asw[3 * 64 * 64];    // 24576 B
    __shared__ __align__(16) unsigned short Bsw[2 * 192 * 64];   // 49152 B
    const int t = threadIdx.x, lane = t & 63, wv8 = t >> 6;
    const int wm = wv8 >> 2, wn = wv8 & 3;           // 2m x 4n
    const int l15 = lane & 15, lq = lane >> 4;
    const int m0 = blockIdx.x * 64;

    int boffs[3];
    #pragma unroll
    for (int s = 0; s < 3; ++s) {
        int row = (wv8 + 8 * s) * 8 + (lane >> 3);
        boffs[s] = row * 192 + ((lane & 7) ^ (lane >> 3)) * 8;
    }
    #pragma unroll
    for (int s = 0; s < 3; ++s)   // B (ct0, k0) -> buf 0
        gload_lds16(Bt + boffs[s], (char*)Bsw + (wv8 + 8 * s) * 1024);

    {   // LN1 in-block: 8 lanes per row, 24 elems each
        int row = t >> 3, oct = t & 7;
        const float* p = Af + (size_t)wperm(m0 + row) * 192 + oct * 24;
        f32x4 v[6];
        float s = 0.f, q = 0.f;
        #pragma unroll
        for (int i = 0; i < 6; ++i) {
            v[i] = *(const f32x4*)(p + i * 4);
            #pragma unroll
            for (int j = 0; j < 4; ++j) { s += v[i][j]; q += v[i][j] * v[i][j]; }
        }
        s += __shfl_xor(s, 1); s += __shfl_xor(s, 2); s += __shfl_xor(s, 4);
        q += __shfl_xor(q, 1); q += __shfl_xor(q, 2); q += __shfl_xor(q, 4);
        float mean = s * (1.f / 192.f);
        float rstd = rsqrtf(q * (1.f / 192.f) - mean * mean + 1e-5f);
        #pragma unroll
        for (int i = 0; i < 6; ++i) {
            int k = oct * 24 + i * 4;
            u16x4 pk;
            #pragma unroll
            for (int j = 0; j < 4; ++j)
                pk[j] = f2b((v[i][j] - mean) * rstd * lng[k + j] + lnb[k + j]);
            int cc = k >> 6, ch = (k >> 2) & 15;
            int byte = cc * 8192 + row * 128 +
                       ((((ch >> 1) ^ (row & 7)) << 4) + ((ch & 1) << 3));
            *(u16x4*)((char*)Asw + byte) = pk;
        }
        asm volatile("s_waitcnt lgkmcnt(0)" ::: "memory");
    }

    const int axor = (l15 & 7) << 4;
    int cur = 0, it = 0;
    for (int ct = 0; ct < NCT; ++ct) {
        f32x4 acc[2][3];
        #pragma unroll
        for (int i = 0; i < 2; ++i)
            #pragma unroll
            for (int j = 0; j < 3; ++j) acc[i][j] = (f32x4){0.f, 0.f, 0.f, 0.f};
        for (int c = 0; c < 3; ++c, ++it) {
            if (it < NCT * 3 - 1) {
                int ctn = (c == 2) ? ct + 1 : ct;
                int cn  = (c == 2) ? 0 : c + 1;
                #pragma unroll
                for (int s = 0; s < 3; ++s)
                    gload_lds16(Bt + (size_t)ctn * 36864 + boffs[s] + cn * 64,
                                (char*)Bsw + (cur ^ 1) * 24576 + (wv8 + 8 * s) * 1024);
                asm volatile("s_waitcnt vmcnt(3)" ::: "memory");
            } else {
                asm volatile("s_waitcnt vmcnt(0)" ::: "memory");
            }
            __builtin_amdgcn_sched_barrier(0);
            __builtin_amdgcn_s_barrier();
            __builtin_amdgcn_sched_barrier(0);
            const char* Al = (const char*)Asw + c * 8192;
            const char* Bl = (const char*)Bsw + cur * 24576;
            #pragma unroll
            for (int kk = 0; kk < 2; ++kk) {
                bf16x8 a[2], bb[3];
                #pragma unroll
                for (int mt = 0; mt < 2; ++mt)
                    a[mt] = *(const bf16x8*)(Al + (wm * 32 + mt * 16 + l15) * 128 +
                                             ((kk << 6) ^ (lq << 4) ^ axor));
                #pragma unroll
                for (int nt = 0; nt < 3; ++nt)
                    bb[nt] = *(const bf16x8*)(Bl + (wn * 48 + nt * 16 + l15) * 128 +
                                              ((kk << 6) ^ (lq << 4) ^ axor));
                #pragma unroll
                for (int mt = 0; mt < 2; ++mt)
                    #pragma unroll
                    for (int nt = 0; nt < 3; ++nt)
                        acc[mt][nt] = __builtin_amdgcn_mfma_f32_16x16x32_bf16(a[mt], bb[nt], acc[mt][nt], 0, 0, 0);
            }
            __builtin_amdgcn_sched_barrier(0);
            __builtin_amdgcn_s_barrier();
            cur ^= 1;
        }
        unsigned short* dst = (ct == 0) ? oq : (ct == 1) ? ok2 : ov;
        float qs = (ct == 0) ? 0.17677669529663689f : 1.0f;
        #pragma unroll
        for (int mt = 0; mt < 2; ++mt)
            #pragma unroll
            for (int nt = 0; nt < 3; ++nt)
                #pragma unroll
                for (int r = 0; r < 4; ++r) {
                    int m = m0 + wm * 32 + mt * 16 + lq * 4 + r;
                    int col = wn * 48 + nt * 16 + l15;
                    float v = (acc[mt][nt][r] + bias[ct * 192 + col]) * qs;
                    int head = col >> 5, d = col & 31;
                    int w = m >> 6, n = m & 63;
                    dst[((size_t)(w * 6 + head) * 64 + n) * 32 + d] = f2b(v);
                }
    }
}

// ---- fused: windowed attention + proj + residual + LN2 + fc1 + gelu -------
// Block = one window. Phase 0: 24 (head,mt) units distributed over ALL 8
// waves (3 units each): vT build -> QK+softmax+P store -> barrier -> PV ->
// barrier -> O into swizzled A panel. Phases 1/2 unchanged.
__global__ __launch_bounds__(512) void attn_proj_fc1(
    const unsigned short* __restrict__ qb, const unsigned short* __restrict__ kb,
    const unsigned short* __restrict__ vb, const float* __restrict__ btab,
    const float* __restrict__ resid,
    const unsigned short* __restrict__ projT, const float* __restrict__ projb,
    const unsigned short* __restrict__ fc1T, const float* __restrict__ fc1b,
    const float* __restrict__ n2g, const float* __restrict__ n2b,
    float* __restrict__ ofp, unsigned short* __restrict__ obf) {
    __shared__ __align__(16) unsigned short Asw[3 * 64 * 64];    // 24576 B
    __shared__ __align__(16) unsigned short Bsw[2 * 192 * 64];   // 49152 B
    __shared__ float scratch[1352];                              // sbias | sred+srow
    const int t = threadIdx.x, lane = t & 63, wv8 = t >> 6;
    const int wm = wv8 >> 2, wn = wv8 & 3;
    const int l15 = lane & 15, lq = lane >> 4;
    const int win = blockIdx.x;
    const int m0 = win * 64;
    const int axor = (l15 & 7) << 4;
    const size_t wbase = (size_t)win * 6;

    // stage per-head bias tables: sbias[h*225+idx] = btab[idx*6+h]
    for (int i = t; i < 1350; i += 512) {
        int h = i / 225, idx = i - h * 225;
        scratch[i] = btab[idx * 6 + h];
    }
    __syncthreads();

    // ---------------- phase 0: attention, 24 units on 8 waves ----------------
    // vT build: 24 tasks (h, quarter)
    #pragma unroll
    for (int s = 0; s < 3; ++s) {
        int u = wv8 + 8 * s;
        int h = u >> 2;
        const unsigned short* vp = vb + (wbase + h) * 2048;
        int c = lane + (u & 3) * 64;
        int mr = c >> 2, d0 = (c & 3) * 8;
        u16x8 v = *(const u16x8*)(vp + mr * 32 + d0);
        #pragma unroll
        for (int j = 0; j < 8; ++j) {
            int row = d0 + j;
            int byte = h * 4096 + row * 128 +
                       (((mr >> 3) ^ (row & 7)) << 4) + (mr & 7) * 2;
            *(unsigned short*)((char*)Asw + byte) = v[j];
        }
    }
    // QK + softmax: 24 units (h, mt)
    #pragma unroll
    for (int s = 0; s < 3; ++s) {
        int u = wv8 + 8 * s;
        int h = u >> 2, mt = u & 3;
        const unsigned short* qp = qb + (wbase + h) * 2048;
        const unsigned short* kp = kb + (wbase + h) * 2048;
        bf16x8 qf = *(const bf16x8*)(qp + (mt * 16 + l15) * 32 + lq * 8);
        f32x4 sc[4];
        #pragma unroll
        for (int nt = 0; nt < 4; ++nt) {
            bf16x8 kf = *(const bf16x8*)(kp + (nt * 16 + l15) * 32 + lq * 8);
            sc[nt] = __builtin_amdgcn_mfma_f32_16x16x32_bf16(
                qf, kf, (f32x4){0.f, 0.f, 0.f, 0.f}, 0, 0, 0);
        }
        #pragma unroll
        for (int r = 0; r < 4; ++r) {
            int n = mt * 16 + lq * 4 + r;
            int ny = n >> 3, nx = n & 7;
            float sv[4];
            float mx = -1e30f;
            #pragma unroll
            for (int nt = 0; nt < 4; ++nt) {
                int m = nt * 16 + l15;
                int idx = (ny - (m >> 3) + 7) * 15 + (nx - (m & 7) + 7);
                float val = sc[nt][r] + scratch[h * 225 + idx];
                sv[nt] = val;
                mx = fmaxf(mx, val);
            }
            #pragma unroll
            for (int off = 1; off < 16; off <<= 1) mx = fmaxf(mx, __shfl_xor(mx, off));
            float sum = 0.f;
            #pragma unroll
            for (int nt = 0; nt < 4; ++nt) { sv[nt] = __expf(sv[nt] - mx); sum += sv[nt]; }
            #pragma unroll
            for (int off = 1; off < 16; off <<= 1) sum += __shfl_xor(sum, off);
            float inv = 1.f / sum;
            #pragma unroll
            for (int nt = 0; nt < 4; ++nt) {
                int col = nt * 16 + l15;
                int byte = h * 8192 + n * 128 +
                           (((col >> 3) ^ (n & 7)) << 4) + (col & 7) * 2;
                *(unsigned short*)((char*)Bsw + byte) = f2b(sv[nt] * inv);
            }
        }
    }
    __syncthreads();   // P + vT visible block-wide
    f32x4 o[3][2];
    #pragma unroll
    for (int i = 0; i < 3; ++i)
        #pragma unroll
        for (int j = 0; j < 2; ++j) o[i][j] = (f32x4){0.f, 0.f, 0.f, 0.f};
    #pragma unroll
    for (int s = 0; s < 3; ++s) {
        int u = wv8 + 8 * s;
        int h = u >> 2, mt = u & 3;
        #pragma unroll
        for (int kk = 0; kk < 2; ++kk) {
            bf16x8 a = *(const bf16x8*)((char*)Bsw + h * 8192 +
                (mt * 16 + l15) * 128 + ((kk << 6) ^ (lq << 4) ^ axor));
            #pragma unroll
            for (int dt = 0; dt < 2; ++dt) {
                bf16x8 b = *(const bf16x8*)((char*)Asw + h * 4096 +
                    (dt * 16 + l15) * 128 + ((kk << 6) ^ (lq << 4) ^ axor));
                o[s][dt] = __builtin_amdgcn_mfma_f32_16x16x32_bf16(a, b, o[s][dt], 0, 0, 0);
            }
        }
    }
    __syncthreads();   // all PV done; Asw free for O panel
    #pragma unroll
    for (int s = 0; s < 3; ++s) {
        int u = wv8 + 8 * s;
        int h = u >> 2, mt = u & 3;
        #pragma unroll
        for (int dt = 0; dt < 2; ++dt)
            #pragma unroll
            for (int r = 0; r < 4; ++r) {
                int row = mt * 16 + lq * 4 + r;
                int k = h * 32 + dt * 16 + l15;
                int cc = k >> 6, k6 = k & 63;
                int byte = cc * 8192 + row * 128 +
                           (((k6 >> 3) ^ (row & 7)) << 4) + (k6 & 7) * 2;
                *(unsigned short*)((char*)Asw + byte) = f2b(o[s][dt][r]);
            }
    }
    int boffs[3];
    #pragma unroll
    for (int s = 0; s < 3; ++s) {
        int row = (wv8 + 8 * s) * 8 + (lane >> 3);
        boffs[s] = row * 192 + ((lane & 7) ^ (lane >> 3)) * 8;
    }
    #pragma unroll
    for (int s = 0; s < 3; ++s)     // proj B chunk 0 -> buf 0
        gload_lds16(projT + boffs[s], (char*)Bsw + (wv8 + 8 * s) * 1024);
    __syncthreads();                // A panel ready; B chunk0 ready (drained)

    int cur = 0;
    // ---------------- phase 1: proj ----------------
    f32x4 acc[2][3];
    #pragma unroll
    for (int i = 0; i < 2; ++i)
        #pragma unroll
        for (int j = 0; j < 3; ++j) acc[i][j] = (f32x4){0.f, 0.f, 0.f, 0.f};
    for (int c = 0; c < 3; ++c) {
        if (c < 2) {
            #pragma unroll
            for (int s = 0; s < 3; ++s)
                gload_lds16(projT + boffs[s] + (c + 1) * 64,
                            (char*)Bsw + (cur ^ 1) * 24576 + (wv8 + 8 * s) * 1024);
        } else {   // prefetch fc1 ct0 chunk0 (lands during epilogue)
            #pragma unroll
            for (int s = 0; s < 3; ++s)
                gload_lds16(fc1T + boffs[s],
                            (char*)Bsw + (cur ^ 1) * 24576 + (wv8 + 8 * s) * 1024);
        }
        asm volatile("s_waitcnt vmcnt(3)" ::: "memory");
        __builtin_amdgcn_sched_barrier(0);
        __builtin_amdgcn_s_barrier();
        __builtin_amdgcn_sched_barrier(0);
        const char* Al = (const char*)Asw + c * 8192;
        const char* Bl = (const char*)Bsw + cur * 24576;
        #pragma unroll
        for (int kk = 0; kk < 2; ++kk) {
            bf16x8 a[2], bb[3];
            #pragma unroll
            for (int mt = 0; mt < 2; ++mt)
                a[mt] = *(const bf16x8*)(Al + (wm * 32 + mt * 16 + l15) * 128 +
                                         ((kk << 6) ^ (lq << 4) ^ axor));
            #pragma unroll
            for (int nt = 0; nt < 3; ++nt)
                bb[nt] = *(const bf16x8*)(Bl + (wn * 48 + nt * 16 + l15) * 128 +
                                          ((kk << 6) ^ (lq << 4) ^ axor));
            #pragma unroll
            for (int mt = 0; mt < 2; ++mt)
                #pragma unroll
                for (int nt = 0; nt < 3; ++nt)
                    acc[mt][nt] = __builtin_amdgcn_mfma_f32_16x16x32_bf16(a[mt], bb[nt], acc[mt][nt], 0, 0, 0);
        }
        __builtin_amdgcn_sched_barrier(0);
        __builtin_amdgcn_s_barrier();
        cur ^= 1;
    }
    // ---- epilogue 1: out write + stats (values held in regs) ----
    float* sred = scratch;          // [64][8]
    float* srow = scratch + 512;    // [64][2]
    float hw[2][3][4];
    #pragma unroll
    for (int mt = 0; mt < 2; ++mt) {
        #pragma unroll
        for (int r = 0; r < 4; ++r) {
            int row = wm * 32 + mt * 16 + lq * 4 + r;
            int r2 = wperm(m0 + row);
            float s = 0.f, q = 0.f;
            #pragma unroll
            for (int nt = 0; nt < 3; ++nt) {
                int col = wn * 48 + nt * 16 + l15;
                size_t idx = (size_t)r2 * 192 + col;
                float wv = resid[idx] + acc[mt][nt][r] + projb[col];
                ofp[idx] = wv;
                hw[mt][nt][r] = wv;
                s += wv;
                q += wv * wv;
            }
            #pragma unroll
            for (int off = 1; off < 16; off <<= 1) {
                s += __shfl_xor(s, off);
                q += __shfl_xor(q, off);
            }
            if (l15 == 0) {
                sred[row * 8 + wn * 2]     = s;
                sred[row * 8 + wn * 2 + 1] = q;
            }
        }
    }
    __syncthreads();
    if (t < 64) {
        float s = sred[t * 8] + sred[t * 8 + 2] + sred[t * 8 + 4] + sred[t * 8 + 6];
        float q = sred[t * 8 + 1] + sred[t * 8 + 3] + sred[t * 8 + 5] + sred[t * 8 + 7];
        float mean = s * (1.f / 192.f);
        float var = q * (1.f / 192.f) - mean * mean;
        srow[t * 2] = mean;
        srow[t * 2 + 1] = rsqrtf(var + 1e-5f);
    }
    __syncthreads();
    {   // normalize held values into swizzled Asw panel
        float g3[3], b3[3];
        #pragma unroll
        for (int nt = 0; nt < 3; ++nt) {
            int col = wn * 48 + nt * 16 + l15;
            g3[nt] = n2g[col];
            b3[nt] = n2b[col];
        }
        #pragma unroll
        for (int mt = 0; mt < 2; ++mt)
            #pragma unroll
            for (int r = 0; r < 4; ++r) {
                int row = wm * 32 + mt * 16 + lq * 4 + r;
                float mean = srow[row * 2], rstd = srow[row * 2 + 1];
                #pragma unroll
                for (int nt = 0; nt < 3; ++nt) {
                    int k = wn * 48 + nt * 16 + l15;
                    float nv = (hw[mt][nt][r] - mean) * rstd * g3[nt] + b3[nt];
                    int cc = k >> 6, k6 = k & 63;
                    int byte = cc * 8192 + row * 128 +
                               (((k6 >> 3) ^ (row & 7)) << 4) + (k6 & 7) * 2;
                    *(unsigned short*)((char*)Asw + byte) = f2b(nv);
                }
            }
    }
    __syncthreads();   // A panel ready (fc1 ct0c0 prefetch also drained)

    // ---------------- phase 2: fc1, NCT = 4 ----------------
    for (int ct = 0; ct < 4; ++ct) {
        f32x4 a2[2][3];
        #pragma unroll
        for (int i = 0; i < 2; ++i)
            #pragma unroll
            for (int j = 0; j < 3; ++j) a2[i][j] = (f32x4){0.f, 0.f, 0.f, 0.f};
        for (int c = 0; c < 3; ++c) {
            int it = ct * 3 + c;
            if (it < 11) {
                int ctn = (c == 2) ? ct + 1 : ct;
                int cn  = (c == 2) ? 0 : c + 1;
                #pragma unroll
                for (int s = 0; s < 3; ++s)
                    gload_lds16(fc1T + (size_t)ctn * 36864 + boffs[s] + cn * 64,
                                (char*)Bsw + (cur ^ 1) * 24576 + (wv8 + 8 * s) * 1024);
                asm volatile("s_waitcnt vmcnt(3)" ::: "memory");
            } else {
                asm volatile("s_waitcnt vmcnt(0)" ::: "memory");
            }
            __builtin_amdgcn_sched_barrier(0);
            __builtin_amdgcn_s_barrier();
            __builtin_amdgcn_sched_barrier(0);
            const char* Al = (const char*)Asw + c * 8192;
            const char* Bl = (const char*)Bsw + cur * 24576;
            #pragma unroll
            for (int kk = 0; kk < 2; ++kk) {
                bf16x8 a[2], bb[3];
                #pragma unroll
                for (int mt = 0; mt < 2; ++mt)
                    a[mt] = *(const bf16x8*)(Al + (wm * 32 + mt * 16 + l15) * 128 +
                                             ((kk << 6) ^ (lq << 4) ^ axor));
                #pragma unroll
                for (int nt = 0; nt < 3; ++nt)
                    bb[nt] = *(const bf16x8*)(Bl + (wn * 48 + nt * 16 + l15) * 128 +
                                              ((kk << 6) ^ (lq << 4) ^ axor));
                #pragma unroll
                for (int mt = 0; mt < 2; ++mt)
                    #pragma unroll
                    for (int nt = 0; nt < 3; ++nt)
                        a2[mt][nt] = __builtin_amdgcn_mfma_f32_16x16x32_bf16(a[mt], bb[nt], a2[mt][nt], 0, 0, 0);
            }
            __builtin_amdgcn_sched_barrier(0);
            __builtin_amdgcn_s_barrier();
            cur ^= 1;
        }
        #pragma unroll
        for (int mt = 0; mt < 2; ++mt)
            #pragma unroll
            for (int nt = 0; nt < 3; ++nt)
                #pragma unroll
                for (int r = 0; r < 4; ++r) {
                    int m = m0 + wm * 32 + mt * 16 + lq * 4 + r;
                    int col = wn * 48 + nt * 16 + l15;
                    obf[(size_t)wperm(m) * 768 + ct * 192 + col] =
                        f2b(gelu_fast(a2[mt][nt][r] + fc1b[ct * 192 + col]));
                }
    }
}

// -------- fused depthwise 3x3 conv + gelu + fc2 + residual ------------------
// v14 (proven 199us): tile 32x*4y, vertical-pair threads share tap weights.
__global__ __launch_bounds__(512) void conv_fc2_v14(
    const unsigned short* __restrict__ m1, const float* __restrict__ dwwTf,
    const float* __restrict__ dwb, const unsigned short* __restrict__ fc2T,
    const float* __restrict__ fc2b, float* __restrict__ out) {
    __shared__ __align__(16) unsigned short Xs[26 * 512];      // 26624 B (13056 used)
    __shared__ __align__(16) unsigned short As[128 * 72];      // 18432 B
    __shared__ __align__(16) unsigned short Bsw[192 * 64];     // 24576 B
    const int t = threadIdx.x;
    const int g = ((blockIdx.x & 7) << 7) + (blockIdx.x >> 3); // 1024 blocks, XCD bands
    const int b = g >> 9, yt = (g >> 3) & 63, xq = g & 7;
    const int y0 = yt * 4, x0 = xq * 32;
    const int cg = t & 7, lx = t >> 3;               // lx in [0,64)
    const int xx = lx & 31, yy0 = lx >> 5;           // output rows yy0, yy0+2
    const size_t ibase = (size_t)b * 65536;

    const int lane = t & 63, wv8 = t >> 6;           // wave 0..7
    const int wm = wv8 >> 1, wn = wv8 & 1;           // 4m x 2n wave grid
    const int l15 = lane & 15, lq = lane >> 4;

    int xoff[4];
    #pragma unroll
    for (int s = 0; s < 4; ++s) {
        int seg = wv8 + 8 * s;
        int e = seg * 512 + lane * 8;
        e = min(e, 13048);
        int row = e / 2176;
        int rem = e - row * 2176;
        int px = rem >> 6, ch = rem & 63;
        int gy = min(max(y0 - 1 + row, 0), 255);
        int gx = min(max(x0 - 1 + px, 0), 255);
        xoff[s] = ((b << 16) + (gy << 8) + gx) * 768 + ch;
    }
    int boff[3];
    #pragma unroll
    for (int s = 0; s < 3; ++s) {
        int row = (wv8 + 8 * s) * 8 + (lane >> 3);
        boff[s] = row * 768 + ((lane & 7) ^ (lane >> 3)) * 8;
    }

    f32x4 acc[2][6];
    #pragma unroll
    for (int i = 0; i < 2; ++i)
        #pragma unroll
        for (int j = 0; j < 6; ++j) acc[i][j] = (f32x4){0.f, 0.f, 0.f, 0.f};

    #pragma unroll
    for (int s = 0; s < 4; ++s)
        if (wv8 + 8 * s < 26)
            gload_lds16(m1 + xoff[s], (char*)Xs + (wv8 + 8 * s) * 1024);
    #pragma unroll
    for (int s = 0; s < 3; ++s)
        gload_lds16(fc2T + boff[s], (char*)Bsw + (wv8 + 8 * s) * 1024);

    const int xb = xx * 128 + cg * 16;
    const int gxp = x0 + xx;
    const bool xok0 = gxp >= 1;
    const bool xok2 = gxp <= 254;
    const int oy0 = y0 + yy0;
    const int o00 = (lq * 16) ^ ((l15 & 7) << 4);
    const int brow = (wn * 96 + l15) * 128;

    for (int k0 = 0; k0 < 768; k0 += 64) {
        const int c0 = k0 + cg * 8;
        asm volatile("s_waitcnt vmcnt(0)" ::: "memory");
        __syncthreads();                               // b1: Xs,Bsw ready
        float a0[8], a1[8];
        #pragma unroll
        for (int j = 0; j < 8; ++j) { a0[j] = 0.f; a1[j] = 0.f; }
        #pragma unroll
        for (int kx = 0; kx < 3; ++kx) {
            if (kx == 0 && !xok0) continue;
            if (kx == 2 && !xok2) continue;
            #pragma unroll
            for (int ky = 0; ky < 3; ++ky) {
                const float* wp = dwwTf + (ky * 3 + kx) * 768 + c0;
                f32x4 w0 = *(const f32x4*)wp;
                f32x4 w1 = *(const f32x4*)(wp + 4);
                if ((unsigned)(oy0 + ky - 1) < 256u) {
                    u16x8 in = *(const u16x8*)((const char*)Xs +
                        (yy0 + ky) * 4352 + xb + kx * 128);
                    #pragma unroll
                    for (int j = 0; j < 4; ++j) {
                        a0[j]     += b2f(in[j]) * w0[j];
                        a0[4 + j] += b2f(in[4 + j]) * w1[j];
                    }
                }
                if ((unsigned)(oy0 + ky + 1) < 256u) {
                    u16x8 in = *(const u16x8*)((const char*)Xs +
                        (yy0 + 2 + ky) * 4352 + xb + kx * 128);
                    #pragma unroll
                    for (int j = 0; j < 4; ++j) {
                        a1[j]     += b2f(in[j]) * w0[j];
                        a1[4 + j] += b2f(in[4 + j]) * w1[j];
                    }
                }
            }
        }
        {
            f32x4 b0 = *(const f32x4*)(dwb + c0);
            f32x4 b1 = *(const f32x4*)(dwb + c0 + 4);
            u16x8 o0, o1;
            #pragma unroll
            for (int j = 0; j < 4; ++j) {
                o0[j]     = f2b(gelu_fast(a0[j] + b0[j]));
                o0[4 + j] = f2b(gelu_fast(a0[4 + j] + b1[j]));
                o1[j]     = f2b(gelu_fast(a1[j] + b0[j]));
                o1[4 + j] = f2b(gelu_fast(a1[4 + j] + b1[j]));
            }
            *(u16x8*)&As[lx * 72 + cg * 8] = o0;
            *(u16x8*)&As[(lx + 64) * 72 + cg * 8] = o1;
        }
        __syncthreads();                               // b2: As ready, Xs free
        if (k0 < 704) {
            #pragma unroll
            for (int s = 0; s < 4; ++s)
                if (wv8 + 8 * s < 26)
                    gload_lds16(m1 + xoff[s] + k0 + 64,
                                (char*)Xs + (wv8 + 8 * s) * 1024);
        }
        #pragma unroll
        for (int kk = 0; kk < 2; ++kk) {
            bf16x8 af[2];
            #pragma unroll
            for (int mt = 0; mt < 2; ++mt)
                af[mt] = *(bf16x8*)&As[(wm * 32 + mt * 16 + l15) * 72 + kk * 32 + lq * 8];
            #pragma unroll
            for (int nt = 0; nt < 6; ++nt) {
                bf16x8 bb = *(const bf16x8*)((const char*)Bsw + brow + nt * 2048 + (o00 ^ (kk << 6)));
                #pragma unroll
                for (int mt = 0; mt < 2; ++mt)
                    acc[mt][nt] = __builtin_amdgcn_mfma_f32_16x16x32_bf16(af[mt], bb, acc[mt][nt], 0, 0, 0);
            }
        }
        __syncthreads();                               // b3: As,Bsw free
        if (k0 < 704) {
            #pragma unroll
            for (int s = 0; s < 3; ++s)
                gload_lds16(fc2T + boff[s] + k0 + 64, (char*)Bsw + (wv8 + 8 * s) * 1024);
        }
    }
    #pragma unroll
    for (int mt = 0; mt < 2; ++mt)
        #pragma unroll
        for (int nt = 0; nt < 6; ++nt)
            #pragma unroll
            for (int r = 0; r < 4; ++r) {
                int ml = wm * 32 + mt * 16 + lq * 4 + r;
                int py = ml >> 5, lxx = ml & 31;
                int col = wn * 96 + nt * 16 + l15;
                size_t idx = (ibase + (size_t)(y0 + py) * 256 + x0 + lxx) * 192 + col;
                out[idx] = out[idx] + acc[mt][nt][r] + fc2b[col];
            }
}

// ---------------- host ----------------
extern "C" void kernel_launch(void* const* d_in, const int* in_sizes, int n_in,
                              void* d_out, int out_size, void* d_ws, size_t ws_size,
                              hipStream_t stream) {
    (void)in_sizes; (void)n_in; (void)out_size; (void)ws_size;
    const float* x     = (const float*)d_in[0];
    const float* scale = (const float*)d_in[1];
    const float* n1g   = (const float*)d_in[2];
    const float* n1b   = (const float*)d_in[3];
    const float* qkvw  = (const float*)d_in[4];
    const float* qkvb  = (const float*)d_in[5];
    const float* projw = (const float*)d_in[6];
    const float* projb = (const float*)d_in[7];
    const float* cw1   = (const float*)d_in[8];
    const float* cb1   = (const float*)d_in[9];
    const float* cw2   = (const float*)d_in[10];
    const float* cb2   = (const float*)d_in[11];
    const float* n2g   = (const float*)d_in[12];
    const float* n2b   = (const float*)d_in[13];
    const float* fc1w  = (const float*)d_in[14];
    const float* fc1b  = (const float*)d_in[15];
    const float* fc2w  = (const float*)d_in[16];
    const float* fc2b  = (const float*)d_in[17];
    const float* dww   = (const float*)d_in[18];
    const float* dwb   = (const float*)d_in[19];
    float* out = (float*)d_out;

    char* ws = (char*)d_ws;
    unsigned short* qkvT  = (unsigned short*)ws;       // [576][192]
    unsigned short* projT = qkvT + 110592;             // [192][192]
    unsigned short* fc1T  = projT + 36864;             // [768][192]
    unsigned short* fc2T  = fc1T + 147456;             // [192][768]
    float* btab   = (float*)(ws + 1048576);            // [225][6]
    float* dwwTf  = (float*)(ws + 1310720);            // [9][768] fp32 tap-major
    unsigned short* pool = (unsigned short*)(ws + 4194304);
    const size_t S = 25165824;                          // 50.3MB slots (ushort count)
    unsigned short* qb = pool;
    unsigned short* kb = pool + S;
    unsigned short* vb = pool + 2 * S;
    unsigned short* m1 = pool + 3 * S;                  // [2*65536][768] bf16

    prep_all<<<1756, 256, 0, stream>>>(
        qkvw, projw, fc1w, fc2w, dww, qkvT, projT, fc1T, fc2T, dwwTf,
        scale, cw1, cb1, cw2, cb2, btab);

    gemm64<0><<<2048, 512, 0, stream>>>(x, n1g, n1b, qkvT, qkvb, qb, kb, vb);
    attn_proj_fc1<<<2048, 512, 0, stream>>>(
        qb, kb, vb, btab, x, projT, projb, fc1T, fc1b, n2g, n2b, out, m1);
    conv_fc2_v14<<<1024, 512, 0, stream>>>(m1, dwwTf, dwb, fc2T, fc2b, out);
}

// Round 24
// 526.904 us; speedup vs baseline: 1.0713x; 1.0105x over previous
//
#include <hip/hip_runtime.h>
#include <hip/hip_bf16.h>

typedef __attribute__((ext_vector_type(8))) short  bf16x8;
typedef __attribute__((ext_vector_type(4))) float  f32x4;
typedef __attribute__((ext_vector_type(8))) unsigned short u16x8;
typedef __attribute__((ext_vector_type(4))) unsigned short u16x4;

__device__ __forceinline__ unsigned short f2b(float f) {
    unsigned int u = __builtin_bit_cast(unsigned int, f);
    u += 0x7FFFu + ((u >> 16) & 1u);
    return (unsigned short)(u >> 16);
}
__device__ __forceinline__ float b2f(unsigned short u) {
    return __builtin_bit_cast(float, (unsigned int)u << 16);
}
// sigmoid-form GELU: x*sigmoid(1.702x). ~5 VALU ops.
__device__ __forceinline__ float gelu_fast(float x) {
    float d = 1.0f + __expf(-1.702f * x);
    return x * __builtin_amdgcn_rcpf(d);
}
// windowed row m -> original row (b*65536 + y*256 + x)
__device__ __forceinline__ int wperm(int m) {
    int w = m >> 6, n = m & 63;
    int b = w >> 10, wy = (w >> 5) & 31, wx = w & 31;
    int y = wy * 8 + (n >> 3), xx = wx * 8 + (n & 7);
    return (b << 16) + (y << 8) + xx;
}

__device__ __forceinline__ void gload_lds16(const void* g, void* l) {
    __builtin_amdgcn_global_load_lds(
        (const __attribute__((address_space(1))) void*)g,
        (__attribute__((address_space(3))) void*)l, 16, 0, 0);
}

// ---------------- consolidated prep: all transposes + cpb in ONE launch -----
__global__ __launch_bounds__(256) void prep_all(
    const float* __restrict__ qkvw, const float* __restrict__ projw,
    const float* __restrict__ fc1w, const float* __restrict__ fc2w,
    const float* __restrict__ dww,
    unsigned short* __restrict__ qkvT, unsigned short* __restrict__ projT,
    unsigned short* __restrict__ fc1T, unsigned short* __restrict__ fc2T,
    float* __restrict__ dwwTf,
    const float* __restrict__ scale, const float* __restrict__ w1,
    const float* __restrict__ b1, const float* __restrict__ w2,
    const float* __restrict__ b2, float* __restrict__ btab) {
    const int bid = blockIdx.x, t = threadIdx.x;
    if (bid < 432) {                       // qkvT [576n][192k]
        int i = bid * 256 + t;
        int n = i / 192, k = i - n * 192;
        qkvT[i] = f2b(qkvw[k * 576 + n]);
    } else if (bid < 576) {                // projT [192n][192k]
        int i = (bid - 432) * 256 + t;
        int n = i / 192, k = i - n * 192;
        projT[i] = f2b(projw[k * 192 + n]);
    } else if (bid < 1152) {               // fc1T [768n][192k]
        int i = (bid - 576) * 256 + t;
        int n = i / 192, k = i - n * 192;
        fc1T[i] = f2b(fc1w[k * 768 + n]);
    } else if (bid < 1728) {               // fc2T [192n][768k]
        int i = (bid - 1152) * 256 + t;
        int n = i / 768, k = i - n * 768;
        fc2T[i] = f2b(fc2w[k * 192 + n]);
    } else if (bid < 1755) {               // dwwTf [9 tap][768 ch] fp32
        int i = (bid - 1728) * 256 + t;
        if (i < 6912) {
            int n = i / 768, k = i - n * 768;
            dwwTf[i] = dww[k * 9 + n];
        }
    } else {                               // cpb bias table (225 threads)
        if (t >= 225) return;
        int i = t / 15, j = t - (t / 15) * 15;
        float ti = (i - 7) * (8.0f / 7.0f);
        float tj = (j - 7) * (8.0f / 7.0f);
        float s0 = scale[0], s1 = scale[1];
        float acc[6];
        #pragma unroll
        for (int h = 0; h < 6; ++h) acc[h] = b2[h];
        for (int k = 0; k < 512; ++k) {
            float hv = ti * w1[k] + tj * w1[512 + k] + s0 * w1[1024 + k] + s1 * w1[1536 + k] + b1[k];
            hv = fmaxf(hv, 0.f);
            #pragma unroll
            for (int h = 0; h < 6; ++h) acc[h] += hv * w2[k * 6 + h];
        }
        #pragma unroll
        for (int h = 0; h < 6; ++h) btab[t * 6 + h] = acc[h];
    }
}

// ---------------- GEMM: M-tile 64, full-K A-panel in LDS, 8 waves ----------
// v2: SINGLE-buffered B (49.2KB LDS -> 3 blocks/CU, 24 waves). Drain schedule
// {vmcnt(0)+bar -> 12 MFMA -> bar -> issue next B} - the v14-conv-proven
// occupancy>pipelining trade. Epilogue overlaps the next B-load flight.
__global__ __launch_bounds__(512) void gemm64_qkv(
    const float* __restrict__ Af,
    const float* __restrict__ lng, const float* __restrict__ lnb,
    const unsigned short* __restrict__ Bt, const float* __restrict__ bias,
    unsigned short* __restrict__ oq, unsigned short* __restrict__ ok2,
    unsigned short* __restrict__ ov) {
    __shared__ __align__(16) unsigned short Asw[3 * 64 * 64];    // 24576 B
    __shared__ __align__(16) unsigned short Bsw[192 * 64];       // 24576 B
    const int t = threadIdx.x, lane = t & 63, wv8 = t >> 6;
    const int wm = wv8 >> 2, wn = wv8 & 3;           // 2m x 4n
    const int l15 = lane & 15, lq = lane >> 4;
    const int m0 = blockIdx.x * 64;

    int boffs[3];
    #pragma unroll
    for (int s = 0; s < 3; ++s) {
        int row = (wv8 + 8 * s) * 8 + (lane >> 3);
        boffs[s] = row * 192 + ((lane & 7) ^ (lane >> 3)) * 8;
    }
    #pragma unroll
    for (int s = 0; s < 3; ++s)   // B (ct0, c0)
        gload_lds16(Bt + boffs[s], (char*)Bsw + (wv8 + 8 * s) * 1024);

    {   // LN1 in-block: 8 lanes per row, 24 elems each
        int row = t >> 3, oct = t & 7;
        const float* p = Af + (size_t)wperm(m0 + row) * 192 + oct * 24;
        f32x4 v[6];
        float s = 0.f, q = 0.f;
        #pragma unroll
        for (int i = 0; i < 6; ++i) {
            v[i] = *(const f32x4*)(p + i * 4);
            #pragma unroll
            for (int j = 0; j < 4; ++j) { s += v[i][j]; q += v[i][j] * v[i][j]; }
        }
        s += __shfl_xor(s, 1); s += __shfl_xor(s, 2); s += __shfl_xor(s, 4);
        q += __shfl_xor(q, 1); q += __shfl_xor(q, 2); q += __shfl_xor(q, 4);
        float mean = s * (1.f / 192.f);
        float rstd = rsqrtf(q * (1.f / 192.f) - mean * mean + 1e-5f);
        #pragma unroll
        for (int i = 0; i < 6; ++i) {
            int k = oct * 24 + i * 4;
            u16x4 pk;
            #pragma unroll
            for (int j = 0; j < 4; ++j)
                pk[j] = f2b((v[i][j] - mean) * rstd * lng[k + j] + lnb[k + j]);
            int cc = k >> 6, ch = (k >> 2) & 15;
            int byte = cc * 8192 + row * 128 +
                       ((((ch >> 1) ^ (row & 7)) << 4) + ((ch & 1) << 3));
            *(u16x4*)((char*)Asw + byte) = pk;
        }
        asm volatile("s_waitcnt lgkmcnt(0)" ::: "memory");
    }

    const int axor = (l15 & 7) << 4;
    int it = 0;
    for (int ct = 0; ct < 3; ++ct) {
        f32x4 acc[2][3];
        #pragma unroll
        for (int i = 0; i < 2; ++i)
            #pragma unroll
            for (int j = 0; j < 3; ++j) acc[i][j] = (f32x4){0.f, 0.f, 0.f, 0.f};
        for (int c = 0; c < 3; ++c, ++it) {
            asm volatile("s_waitcnt vmcnt(0)" ::: "memory");
            __builtin_amdgcn_sched_barrier(0);
            __builtin_amdgcn_s_barrier();
            __builtin_amdgcn_sched_barrier(0);
            const char* Al = (const char*)Asw + c * 8192;
            #pragma unroll
            for (int kk = 0; kk < 2; ++kk) {
                bf16x8 a[2], bb[3];
                #pragma unroll
                for (int mt = 0; mt < 2; ++mt)
                    a[mt] = *(const bf16x8*)(Al + (wm * 32 + mt * 16 + l15) * 128 +
                                             ((kk << 6) ^ (lq << 4) ^ axor));
                #pragma unroll
                for (int nt = 0; nt < 3; ++nt)
                    bb[nt] = *(const bf16x8*)((const char*)Bsw +
                                              (wn * 48 + nt * 16 + l15) * 128 +
                                              ((kk << 6) ^ (lq << 4) ^ axor));
                #pragma unroll
                for (int mt = 0; mt < 2; ++mt)
                    #pragma unroll
                    for (int nt = 0; nt < 3; ++nt)
                        acc[mt][nt] = __builtin_amdgcn_mfma_f32_16x16x32_bf16(a[mt], bb[nt], acc[mt][nt], 0, 0, 0);
            }
            __builtin_amdgcn_sched_barrier(0);
            __builtin_amdgcn_s_barrier();
            __builtin_amdgcn_sched_barrier(0);
            if (it < 8) {      // issue next B into the (now free) single buffer
                int ctn = (c == 2) ? ct + 1 : ct;
                int cn  = (c == 2) ? 0 : c + 1;
                #pragma unroll
                for (int s = 0; s < 3; ++s)
                    gload_lds16(Bt + (size_t)ctn * 36864 + boffs[s] + cn * 64,
                                (char*)Bsw + (wv8 + 8 * s) * 1024);
            }
        }
        unsigned short* dst = (ct == 0) ? oq : (ct == 1) ? ok2 : ov;
        float qs = (ct == 0) ? 0.17677669529663689f : 1.0f;
        #pragma unroll
        for (int mt = 0; mt < 2; ++mt)
            #pragma unroll
            for (int nt = 0; nt < 3; ++nt)
                #pragma unroll
                for (int r = 0; r < 4; ++r) {
                    int m = m0 + wm * 32 + mt * 16 + lq * 4 + r;
                    int col = wn * 48 + nt * 16 + l15;
                    float v = (acc[mt][nt][r] + bias[ct * 192 + col]) * qs;
                    int head = col >> 5, d = col & 31;
                    int w = m >> 6, n = m & 63;
                    dst[((size_t)(w * 6 + head) * 64 + n) * 32 + d] = f2b(v);
                }
    }
}

// ---- fused: windowed attention + proj + residual + LN2 + fc1 + gelu -------
// Block = one window. Phase 0: 24 (head,mt) units on 8 waves; softmax WITHOUT
// max-subtraction (scores provably bounded ~|2|; identity in fp32); sbias
// staging overlapped with vT build. Phases 1/2 unchanged.
__global__ __launch_bounds__(512) void attn_proj_fc1(
    const unsigned short* __restrict__ qb, const unsigned short* __restrict__ kb,
    const unsigned short* __restrict__ vb, const float* __restrict__ btab,
    const float* __restrict__ resid,
    const unsigned short* __restrict__ projT, const float* __restrict__ projb,
    const unsigned short* __restrict__ fc1T, const float* __restrict__ fc1b,
    const float* __restrict__ n2g, const float* __restrict__ n2b,
    float* __restrict__ ofp, unsigned short* __restrict__ obf) {
    __shared__ __align__(16) unsigned short Asw[3 * 64 * 64];    // 24576 B
    __shared__ __align__(16) unsigned short Bsw[2 * 192 * 64];   // 49152 B
    __shared__ float scratch[1352];                              // sbias | sred+srow
    const int t = threadIdx.x, lane = t & 63, wv8 = t >> 6;
    const int wm = wv8 >> 2, wn = wv8 & 3;
    const int l15 = lane & 15, lq = lane >> 4;
    const int win = blockIdx.x;
    const int m0 = win * 64;
    const int axor = (l15 & 7) << 4;
    const size_t wbase = (size_t)win * 6;

    // stage per-head bias tables: sbias[h*225+idx] = btab[idx*6+h]
    for (int i = t; i < 1350; i += 512) {
        int h = i / 225, idx = i - h * 225;
        scratch[i] = btab[idx * 6 + h];
    }
    // vT build: 24 tasks (h, quarter) — overlaps sbias staging
    #pragma unroll
    for (int s = 0; s < 3; ++s) {
        int u = wv8 + 8 * s;
        int h = u >> 2;
        const unsigned short* vp = vb + (wbase + h) * 2048;
        int c = lane + (u & 3) * 64;
        int mr = c >> 2, d0 = (c & 3) * 8;
        u16x8 v = *(const u16x8*)(vp + mr * 32 + d0);
        #pragma unroll
        for (int j = 0; j < 8; ++j) {
            int row = d0 + j;
            int byte = h * 4096 + row * 128 +
                       (((mr >> 3) ^ (row & 7)) << 4) + (mr & 7) * 2;
            *(unsigned short*)((char*)Asw + byte) = v[j];
        }
    }
    __syncthreads();   // sbias + vT visible

    // QK + softmax (no max-sub): 24 units (h, mt)
    #pragma unroll
    for (int s = 0; s < 3; ++s) {
        int u = wv8 + 8 * s;
        int h = u >> 2, mt = u & 3;
        const unsigned short* qp = qb + (wbase + h) * 2048;
        const unsigned short* kp = kb + (wbase + h) * 2048;
        bf16x8 qf = *(const bf16x8*)(qp + (mt * 16 + l15) * 32 + lq * 8);
        f32x4 sc[4];
        #pragma unroll
        for (int nt = 0; nt < 4; ++nt) {
            bf16x8 kf = *(const bf16x8*)(kp + (nt * 16 + l15) * 32 + lq * 8);
            sc[nt] = __builtin_amdgcn_mfma_f32_16x16x32_bf16(
                qf, kf, (f32x4){0.f, 0.f, 0.f, 0.f}, 0, 0, 0);
        }
        #pragma unroll
        for (int r = 0; r < 4; ++r) {
            int n = mt * 16 + lq * 4 + r;
            int ny = n >> 3, nx = n & 7;
            float sv[4];
            float sum = 0.f;
            #pragma unroll
            for (int nt = 0; nt < 4; ++nt) {
                int m = nt * 16 + l15;
                int idx = (ny - (m >> 3) + 7) * 15 + (nx - (m & 7) + 7);
                sv[nt] = __expf(sc[nt][r] + scratch[h * 225 + idx]);
                sum += sv[nt];
            }
            #pragma unroll
            for (int off = 1; off < 16; off <<= 1) sum += __shfl_xor(sum, off);
            float inv = 1.f / sum;
            #pragma unroll
            for (int nt = 0; nt < 4; ++nt) {
                int col = nt * 16 + l15;
                int byte = h * 8192 + n * 128 +
                           (((col >> 3) ^ (n & 7)) << 4) + (col & 7) * 2;
                *(unsigned short*)((char*)Bsw + byte) = f2b(sv[nt] * inv);
            }
        }
    }
    __syncthreads();   // P visible block-wide
    f32x4 o[3][2];
    #pragma unroll
    for (int i = 0; i < 3; ++i)
        #pragma unroll
        for (int j = 0; j < 2; ++j) o[i][j] = (f32x4){0.f, 0.f, 0.f, 0.f};
    #pragma unroll
    for (int s = 0; s < 3; ++s) {
        int u = wv8 + 8 * s;
        int h = u >> 2, mt = u & 3;
        #pragma unroll
        for (int kk = 0; kk < 2; ++kk) {
            bf16x8 a = *(const bf16x8*)((char*)Bsw + h * 8192 +
                (mt * 16 + l15) * 128 + ((kk << 6) ^ (lq << 4) ^ axor));
            #pragma unroll
            for (int dt = 0; dt < 2; ++dt) {
                bf16x8 b = *(const bf16x8*)((char*)Asw + h * 4096 +
                    (dt * 16 + l15) * 128 + ((kk << 6) ^ (lq << 4) ^ axor));
                o[s][dt] = __builtin_amdgcn_mfma_f32_16x16x32_bf16(a, b, o[s][dt], 0, 0, 0);
            }
        }
    }
    __syncthreads();   // all PV done; Asw free for O panel
    #pragma unroll
    for (int s = 0; s < 3; ++s) {
        int u = wv8 + 8 * s;
        int h = u >> 2, mt = u & 3;
        #pragma unroll
        for (int dt = 0; dt < 2; ++dt)
            #pragma unroll
            for (int r = 0; r < 4; ++r) {
                int row = mt * 16 + lq * 4 + r;
                int k = h * 32 + dt * 16 + l15;
                int cc = k >> 6, k6 = k & 63;
                int byte = cc * 8192 + row * 128 +
                           (((k6 >> 3) ^ (row & 7)) << 4) + (k6 & 7) * 2;
                *(unsigned short*)((char*)Asw + byte) = f2b(o[s][dt][r]);
            }
    }
    int boffs[3];
    #pragma unroll
    for (int s = 0; s < 3; ++s) {
        int row = (wv8 + 8 * s) * 8 + (lane >> 3);
        boffs[s] = row * 192 + ((lane & 7) ^ (lane >> 3)) * 8;
    }
    #pragma unroll
    for (int s = 0; s < 3; ++s)     // proj B chunk 0 -> buf 0
        gload_lds16(projT + boffs[s], (char*)Bsw + (wv8 + 8 * s) * 1024);
    __syncthreads();                // A panel ready; B chunk0 ready (drained)

    int cur = 0;
    // ---------------- phase 1: proj ----------------
    f32x4 acc[2][3];
    #pragma unroll
    for (int i = 0; i < 2; ++i)
        #pragma unroll
        for (int j = 0; j < 3; ++j) acc[i][j] = (f32x4){0.f, 0.f, 0.f, 0.f};
    for (int c = 0; c < 3; ++c) {
        if (c < 2) {
            #pragma unroll
            for (int s = 0; s < 3; ++s)
                gload_lds16(projT + boffs[s] + (c + 1) * 64,
                            (char*)Bsw + (cur ^ 1) * 24576 + (wv8 + 8 * s) * 1024);
        } else {   // prefetch fc1 ct0 chunk0 (lands during epilogue)
            #pragma unroll
            for (int s = 0; s < 3; ++s)
                gload_lds16(fc1T + boffs[s],
                            (char*)Bsw + (cur ^ 1) * 24576 + (wv8 + 8 * s) * 1024);
        }
        asm volatile("s_waitcnt vmcnt(3)" ::: "memory");
        __builtin_amdgcn_sched_barrier(0);
        __builtin_amdgcn_s_barrier();
        __builtin_amdgcn_sched_barrier(0);
        const char* Al = (const char*)Asw + c * 8192;
        const char* Bl = (const char*)Bsw + cur * 24576;
        #pragma unroll
        for (int kk = 0; kk < 2; ++kk) {
            bf16x8 a[2], bb[3];
            #pragma unroll
            for (int mt = 0; mt < 2; ++mt)
                a[mt] = *(const bf16x8*)(Al + (wm * 32 + mt * 16 + l15) * 128 +
                                         ((kk << 6) ^ (lq << 4) ^ axor));
            #pragma unroll
            for (int nt = 0; nt < 3; ++nt)
                bb[nt] = *(const bf16x8*)(Bl + (wn * 48 + nt * 16 + l15) * 128 +
                                          ((kk << 6) ^ (lq << 4) ^ axor));
            #pragma unroll
            for (int mt = 0; mt < 2; ++mt)
                #pragma unroll
                for (int nt = 0; nt < 3; ++nt)
                    acc[mt][nt] = __builtin_amdgcn_mfma_f32_16x16x32_bf16(a[mt], bb[nt], acc[mt][nt], 0, 0, 0);
        }
        __builtin_amdgcn_sched_barrier(0);
        __builtin_amdgcn_s_barrier();
        cur ^= 1;
    }
    // ---- epilogue 1: out write + stats (values held in regs) ----
    float* sred = scratch;          // [64][8]
    float* srow = scratch + 512;    // [64][2]
    float hw[2][3][4];
    #pragma unroll
    for (int mt = 0; mt < 2; ++mt) {
        #pragma unroll
        for (int r = 0; r < 4; ++r) {
            int row = wm * 32 + mt * 16 + lq * 4 + r;
            int r2 = wperm(m0 + row);
            float s = 0.f, q = 0.f;
            #pragma unroll
            for (int nt = 0; nt < 3; ++nt) {
                int col = wn * 48 + nt * 16 + l15;
                size_t idx = (size_t)r2 * 192 + col;
                float wv = resid[idx] + acc[mt][nt][r] + projb[col];
                ofp[idx] = wv;
                hw[mt][nt][r] = wv;
                s += wv;
                q += wv * wv;
            }
            #pragma unroll
            for (int off = 1; off < 16; off <<= 1) {
                s += __shfl_xor(s, off);
                q += __shfl_xor(q, off);
            }
            if (l15 == 0) {
                sred[row * 8 + wn * 2]     = s;
                sred[row * 8 + wn * 2 + 1] = q;
            }
        }
    }
    __syncthreads();
    if (t < 64) {
        float s = sred[t * 8] + sred[t * 8 + 2] + sred[t * 8 + 4] + sred[t * 8 + 6];
        float q = sred[t * 8 + 1] + sred[t * 8 + 3] + sred[t * 8 + 5] + sred[t * 8 + 7];
        float mean = s * (1.f / 192.f);
        float var = q * (1.f / 192.f) - mean * mean;
        srow[t * 2] = mean;
        srow[t * 2 + 1] = rsqrtf(var + 1e-5f);
    }
    __syncthreads();
    {   // normalize held values into swizzled Asw panel
        float g3[3], b3[3];
        #pragma unroll
        for (int nt = 0; nt < 3; ++nt) {
            int col = wn * 48 + nt * 16 + l15;
            g3[nt] = n2g[col];
            b3[nt] = n2b[col];
        }
        #pragma unroll
        for (int mt = 0; mt < 2; ++mt)
            #pragma unroll
            for (int r = 0; r < 4; ++r) {
                int row = wm * 32 + mt * 16 + lq * 4 + r;
                float mean = srow[row * 2], rstd = srow[row * 2 + 1];
                #pragma unroll
                for (int nt = 0; nt < 3; ++nt) {
                    int k = wn * 48 + nt * 16 + l15;
                    float nv = (hw[mt][nt][r] - mean) * rstd * g3[nt] + b3[nt];
                    int cc = k >> 6, k6 = k & 63;
                    int byte = cc * 8192 + row * 128 +
                               (((k6 >> 3) ^ (row & 7)) << 4) + (k6 & 7) * 2;
                    *(unsigned short*)((char*)Asw + byte) = f2b(nv);
                }
            }
    }
    __syncthreads();   // A panel ready (fc1 ct0c0 prefetch also drained)

    // ---------------- phase 2: fc1, NCT = 4 ----------------
    for (int ct = 0; ct < 4; ++ct) {
        f32x4 a2[2][3];
        #pragma unroll
        for (int i = 0; i < 2; ++i)
            #pragma unroll
            for (int j = 0; j < 3; ++j) a2[i][j] = (f32x4){0.f, 0.f, 0.f, 0.f};
        for (int c = 0; c < 3; ++c) {
            int it = ct * 3 + c;
            if (it < 11) {
                int ctn = (c == 2) ? ct + 1 : ct;
                int cn  = (c == 2) ? 0 : c + 1;
                #pragma unroll
                for (int s = 0; s < 3; ++s)
                    gload_lds16(fc1T + (size_t)ctn * 36864 + boffs[s] + cn * 64,
                                (char*)Bsw + (cur ^ 1) * 24576 + (wv8 + 8 * s) * 1024);
                asm volatile("s_waitcnt vmcnt(3)" ::: "memory");
            } else {
                asm volatile("s_waitcnt vmcnt(0)" ::: "memory");
            }
            __builtin_amdgcn_sched_barrier(0);
            __builtin_amdgcn_s_barrier();
            __builtin_amdgcn_sched_barrier(0);
            const char* Al = (const char*)Asw + c * 8192;
            const char* Bl = (const char*)Bsw + cur * 24576;
            #pragma unroll
            for (int kk = 0; kk < 2; ++kk) {
                bf16x8 a[2], bb[3];
                #pragma unroll
                for (int mt = 0; mt < 2; ++mt)
                    a[mt] = *(const bf16x8*)(Al + (wm * 32 + mt * 16 + l15) * 128 +
                                             ((kk << 6) ^ (lq << 4) ^ axor));
                #pragma unroll
                for (int nt = 0; nt < 3; ++nt)
                    bb[nt] = *(const bf16x8*)(Bl + (wn * 48 + nt * 16 + l15) * 128 +
                                              ((kk << 6) ^ (lq << 4) ^ axor));
                #pragma unroll
                for (int mt = 0; mt < 2; ++mt)
                    #pragma unroll
                    for (int nt = 0; nt < 3; ++nt)
                        a2[mt][nt] = __builtin_amdgcn_mfma_f32_16x16x32_bf16(a[mt], bb[nt], a2[mt][nt], 0, 0, 0);
            }
            __builtin_amdgcn_sched_barrier(0);
            __builtin_amdgcn_s_barrier();
            cur ^= 1;
        }
        #pragma unroll
        for (int mt = 0; mt < 2; ++mt)
            #pragma unroll
            for (int nt = 0; nt < 3; ++nt)
                #pragma unroll
                for (int r = 0; r < 4; ++r) {
                    int m = m0 + wm * 32 + mt * 16 + lq * 4 + r;
                    int col = wn * 48 + nt * 16 + l15;
                    obf[(size_t)wperm(m) * 768 + ct * 192 + col] =
                        f2b(gelu_fast(a2[mt][nt][r] + fc1b[ct * 192 + col]));
                }
    }
}

// -------- fused depthwise 3x3 conv + gelu + fc2 + residual ------------------
// v14 (proven 199us): tile 32x*4y, vertical-pair threads share tap weights.
__global__ __launch_bounds__(512) void conv_fc2_v14(
    const unsigned short* __restrict__ m1, const float* __restrict__ dwwTf,
    const float* __restrict__ dwb, const unsigned short* __restrict__ fc2T,
    const float* __restrict__ fc2b, float* __restrict__ out) {
    __shared__ __align__(16) unsigned short Xs[26 * 512];      // 26624 B
    __shared__ __align__(16) unsigned short As[128 * 72];      // 18432 B
    __shared__ __align__(16) unsigned short Bsw[192 * 64];     // 24576 B
    const int t = threadIdx.x;
    const int g = ((blockIdx.x & 7) << 7) + (blockIdx.x >> 3); // 1024 blocks, XCD bands
    const int b = g >> 9, yt = (g >> 3) & 63, xq = g & 7;
    const int y0 = yt * 4, x0 = xq * 32;
    const int cg = t & 7, lx = t >> 3;               // lx in [0,64)
    const int xx = lx & 31, yy0 = lx >> 5;           // output rows yy0, yy0+2
    const size_t ibase = (size_t)b * 65536;

    const int lane = t & 63, wv8 = t >> 6;           // wave 0..7
    const int wm = wv8 >> 1, wn = wv8 & 1;           // 4m x 2n wave grid
    const int l15 = lane & 15, lq = lane >> 4;

    int xoff[4];
    #pragma unroll
    for (int s = 0; s < 4; ++s) {
        int seg = wv8 + 8 * s;
        int e = seg * 512 + lane * 8;
        e = min(e, 13048);
        int row = e / 2176;
        int rem = e - row * 2176;
        int px = rem >> 6, ch = rem & 63;
        int gy = min(max(y0 - 1 + row, 0), 255);
        int gx = min(max(x0 - 1 + px, 0), 255);
        xoff[s] = ((b << 16) + (gy << 8) + gx) * 768 + ch;
    }
    int boff[3];
    #pragma unroll
    for (int s = 0; s < 3; ++s) {
        int row = (wv8 + 8 * s) * 8 + (lane >> 3);
        boff[s] = row * 768 + ((lane & 7) ^ (lane >> 3)) * 8;
    }

    f32x4 acc[2][6];
    #pragma unroll
    for (int i = 0; i < 2; ++i)
        #pragma unroll
        for (int j = 0; j < 6; ++j) acc[i][j] = (f32x4){0.f, 0.f, 0.f, 0.f};

    #pragma unroll
    for (int s = 0; s < 4; ++s)
        if (wv8 + 8 * s < 26)
            gload_lds16(m1 + xoff[s], (char*)Xs + (wv8 + 8 * s) * 1024);
    #pragma unroll
    for (int s = 0; s < 3; ++s)
        gload_lds16(fc2T + boff[s], (char*)Bsw + (wv8 + 8 * s) * 1024);

    const int xb = xx * 128 + cg * 16;
    const int gxp = x0 + xx;
    const bool xok0 = gxp >= 1;
    const bool xok2 = gxp <= 254;
    const int oy0 = y0 + yy0;
    const int o00 = (lq * 16) ^ ((l15 & 7) << 4);
    const int brow = (wn * 96 + l15) * 128;

    for (int k0 = 0; k0 < 768; k0 += 64) {
        const int c0 = k0 + cg * 8;
        asm volatile("s_waitcnt vmcnt(0)" ::: "memory");
        __syncthreads();                               // b1: Xs,Bsw ready
        float a0[8], a1[8];
        #pragma unroll
        for (int j = 0; j < 8; ++j) { a0[j] = 0.f; a1[j] = 0.f; }
        #pragma unroll
        for (int kx = 0; kx < 3; ++kx) {
            if (kx == 0 && !xok0) continue;
            if (kx == 2 && !xok2) continue;
            #pragma unroll
            for (int ky = 0; ky < 3; ++ky) {
                const float* wp = dwwTf + (ky * 3 + kx) * 768 + c0;
                f32x4 w0 = *(const f32x4*)wp;
                f32x4 w1 = *(const f32x4*)(wp + 4);
                if ((unsigned)(oy0 + ky - 1) < 256u) {
                    u16x8 in = *(const u16x8*)((const char*)Xs +
                        (yy0 + ky) * 4352 + xb + kx * 128);
                    #pragma unroll
                    for (int j = 0; j < 4; ++j) {
                        a0[j]     += b2f(in[j]) * w0[j];
                        a0[4 + j] += b2f(in[4 + j]) * w1[j];
                    }
                }
                if ((unsigned)(oy0 + ky + 1) < 256u) {
                    u16x8 in = *(const u16x8*)((const char*)Xs +
                        (yy0 + 2 + ky) * 4352 + xb + kx * 128);
                    #pragma unroll
                    for (int j = 0; j < 4; ++j) {
                        a1[j]     += b2f(in[j]) * w0[j];
                        a1[4 + j] += b2f(in[4 + j]) * w1[j];
                    }
                }
            }
        }
        {
            f32x4 b0 = *(const f32x4*)(dwb + c0);
            f32x4 b1 = *(const f32x4*)(dwb + c0 + 4);
            u16x8 o0, o1;
            #pragma unroll
            for (int j = 0; j < 4; ++j) {
                o0[j]     = f2b(gelu_fast(a0[j] + b0[j]));
                o0[4 + j] = f2b(gelu_fast(a0[4 + j] + b1[j]));
                o1[j]     = f2b(gelu_fast(a1[j] + b0[j]));
                o1[4 + j] = f2b(gelu_fast(a1[4 + j] + b1[j]));
            }
            *(u16x8*)&As[lx * 72 + cg * 8] = o0;
            *(u16x8*)&As[(lx + 64) * 72 + cg * 8] = o1;
        }
        __syncthreads();                               // b2: As ready, Xs free
        if (k0 < 704) {
            #pragma unroll
            for (int s = 0; s < 4; ++s)
                if (wv8 + 8 * s < 26)
                    gload_lds16(m1 + xoff[s] + k0 + 64,
                                (char*)Xs + (wv8 + 8 * s) * 1024);
        }
        #pragma unroll
        for (int kk = 0; kk < 2; ++kk) {
            bf16x8 af[2];
            #pragma unroll
            for (int mt = 0; mt < 2; ++mt)
                af[mt] = *(bf16x8*)&As[(wm * 32 + mt * 16 + l15) * 72 + kk * 32 + lq * 8];
            #pragma unroll
            for (int nt = 0; nt < 6; ++nt) {
                bf16x8 bb = *(const bf16x8*)((const char*)Bsw + brow + nt * 2048 + (o00 ^ (kk << 6)));
                #pragma unroll
                for (int mt = 0; mt < 2; ++mt)
                    acc[mt][nt] = __builtin_amdgcn_mfma_f32_16x16x32_bf16(af[mt], bb, acc[mt][nt], 0, 0, 0);
            }
        }
        __syncthreads();                               // b3: As,Bsw free
        if (k0 < 704) {
            #pragma unroll
            for (int s = 0; s < 3; ++s)
                gload_lds16(fc2T + boff[s] + k0 + 64, (char*)Bsw + (wv8 + 8 * s) * 1024);
        }
    }
    #pragma unroll
    for (int mt = 0; mt < 2; ++mt)
        #pragma unroll
        for (int nt = 0; nt < 6; ++nt)
            #pragma unroll
            for (int r = 0; r < 4; ++r) {
                int ml = wm * 32 + mt * 16 + lq * 4 + r;
                int py = ml >> 5, lxx = ml & 31;
                int col = wn * 96 + nt * 16 + l15;
                size_t idx = (ibase + (size_t)(y0 + py) * 256 + x0 + lxx) * 192 + col;
                out[idx] = out[idx] + acc[mt][nt][r] + fc2b[col];
            }
}

// ---------------- host ----------------
extern "C" void kernel_launch(void* const* d_in, const int* in_sizes, int n_in,
                              void* d_out, int out_size, void* d_ws, size_t ws_size,
                              hipStream_t stream) {
    (void)in_sizes; (void)n_in; (void)out_size; (void)ws_size;
    const float* x     = (const float*)d_in[0];
    const float* scale = (const float*)d_in[1];
    const float* n1g   = (const float*)d_in[2];
    const float* n1b   = (const float*)d_in[3];
    const float* qkvw  = (const float*)d_in[4];
    const float* qkvb  = (const float*)d_in[5];
    const float* projw = (const float*)d_in[6];
    const float* projb = (const float*)d_in[7];
    const float* cw1   = (const float*)d_in[8];
    const float* cb1   = (const float*)d_in[9];
    const float* cw2   = (const float*)d_in[10];
    const float* cb2   = (const float*)d_in[11];
    const float* n2g   = (const float*)d_in[12];
    const float* n2b   = (const float*)d_in[13];
    const float* fc1w  = (const float*)d_in[14];
    const float* fc1b  = (const float*)d_in[15];
    const float* fc2w  = (const float*)d_in[16];
    const float* fc2b  = (const float*)d_in[17];
    const float* dww   = (const float*)d_in[18];
    const float* dwb   = (const float*)d_in[19];
    float* out = (float*)d_out;

    char* ws = (char*)d_ws;
    unsigned short* qkvT  = (unsigned short*)ws;       // [576][192]
    unsigned short* projT = qkvT + 110592;             // [192][192]
    unsigned short* fc1T  = projT + 36864;             // [768][192]
    unsigned short* fc2T  = fc1T + 147456;             // [192][768]
    float* btab   = (float*)(ws + 1048576);            // [225][6]
    float* dwwTf  = (float*)(ws + 1310720);            // [9][768] fp32 tap-major
    unsigned short* pool = (unsigned short*)(ws + 4194304);
    const size_t S = 25165824;                          // 50.3MB slots (ushort count)
    unsigned short* qb = pool;
    unsigned short* kb = pool + S;
    unsigned short* vb = pool + 2 * S;
    unsigned short* m1 = pool + 3 * S;                  // [2*65536][768] bf16

    prep_all<<<1756, 256, 0, stream>>>(
        qkvw, projw, fc1w, fc2w, dww, qkvT, projT, fc1T, fc2T, dwwTf,
        scale, cw1, cb1, cw2, cb2, btab);

    gemm64_qkv<<<2048, 512, 0, stream>>>(x, n1g, n1b, qkvT, qkvb, qb, kb, vb);
    attn_proj_fc1<<<2048, 512, 0, stream>>>(
        qb, kb, vb, btab, x, projT, projb, fc1T, fc1b, n2g, n2b, out, m1);
    conv_fc2_v14<<<1024, 512, 0, stream>>>(m1, dwwTf, dwb, fc2T, fc2b, out);
}